// Round 1
// baseline (1091.269 us; speedup 1.0000x reference)
//
#include <hip/hip_runtime.h>
#include <math.h>

#define Hd 32
#define NEG 0.2f

__device__ __forceinline__ unsigned enc_f(float f) {
    unsigned b = __float_as_uint(f);
    return (b & 0x80000000u) ? ~b : (b | 0x80000000u);
}
__device__ __forceinline__ float dec_f(unsigned k) {
    unsigned b = (k & 0x80000000u) ? (k ^ 0x80000000u) : ~k;
    return __uint_as_float(b);
}
__device__ __forceinline__ float lrelu(float x) { return x > 0.f ? x : NEG * x; }

// K1: h = act(x) @ W.T ; a_s = h@att_src ; a_d = h@att_dst ; m_enc init with self-loop score
template<bool RELU>
__global__ void k_node_proj(const float* __restrict__ x, const float* __restrict__ W,
                            const float* __restrict__ att_s, const float* __restrict__ att_d,
                            float* __restrict__ h, float* __restrict__ as_, float* __restrict__ ad_,
                            unsigned* __restrict__ menc, int N)
{
    __shared__ float Wl[Hd][Hd + 1];   // +1 pad: lanes j=0..31 hit distinct banks
    __shared__ float xr[8][Hd];
    int tid = threadIdx.x;
    for (int i = tid; i < Hd * Hd; i += 256) Wl[i >> 5][i & 31] = W[i];
    int li = tid >> 5, j = tid & 31;
    int node = blockIdx.x * 8 + li;
    float v = 0.f;
    if (node < N) v = x[(size_t)node * Hd + j];
    if (RELU) v = fmaxf(v, 0.f);
    xr[li][j] = v;
    __syncthreads();
    if (node >= N) return;
    float a = 0.f;
#pragma unroll
    for (int k = 0; k < Hd; k++) a += xr[li][k] * Wl[j][k];
    h[(size_t)node * Hd + j] = a;
    float s = a * att_s[j], d = a * att_d[j];
#pragma unroll
    for (int m = 16; m > 0; m >>= 1) { s += __shfl_xor(s, m, 32); d += __shfl_xor(d, m, 32); }
    if (j == 0) {
        as_[node] = s; ad_[node] = d;
        menc[node] = enc_f(lrelu(s + d));   // self-loop edge seeds the segment max
    }
}

// K2: per real edge: e = leaky_relu(a_s[src]+a_d[dst]); store; atomicMax into dst
__global__ void k_edge_max(const int* __restrict__ src, const int* __restrict__ dst,
                           const float* __restrict__ as_, const float* __restrict__ ad_,
                           float* __restrict__ e_out, unsigned* __restrict__ menc, int E)
{
    int i = blockIdx.x * 256 + threadIdx.x;
    if (i >= E) return;
    int s = src[i], d = dst[i];
    float e = lrelu(as_[s] + ad_[d]);
    e_out[i] = e;
    atomicMax(&menc[d], enc_f(e));
}

// K3: seed denom and unnormalized accumulator with the self-loop term (full overwrite)
__global__ void k_node_init(const float* __restrict__ h, const float* __restrict__ as_,
                            const float* __restrict__ ad_, const unsigned* __restrict__ menc,
                            float* __restrict__ den, float* __restrict__ acc, int N)
{
    int idx = blockIdx.x * 256 + threadIdx.x;
    int node = idx >> 5;
    if (node >= N) return;
    int j = idx & 31;
    float m = dec_f(menc[node]);
    float p = expf(lrelu(as_[node] + ad_[node]) - m);
    if (j == 0) den[node] = p;
    acc[(size_t)node * Hd + j] = p * h[(size_t)node * Hd + j];
}

// K4: 32 lanes per edge: p = exp(e - m[dst]); denom += p; acc[dst] += p * h[src]
__global__ void k_edge_scatter(const int* __restrict__ src, const int* __restrict__ dst,
                               const float* __restrict__ e_in, const unsigned* __restrict__ menc,
                               const float* __restrict__ h, float* __restrict__ den,
                               float* __restrict__ acc, int E)
{
    int idx = blockIdx.x * 256 + threadIdx.x;
    int eid = idx >> 5;
    if (eid >= E) return;
    int j = idx & 31;
    int d = dst[eid], s = src[eid];
    float p = expf(e_in[eid] - dec_f(menc[d]));
    if (j == 0) atomicAdd(&den[d], p);
    atomicAdd(&acc[(size_t)d * Hd + j], p * h[(size_t)s * Hd + j]);
}

// K5a: row = acc/denom + bias -> GRU0 -> GRU1 -> out  (h_prev = 0, so gh = bhh)
__global__ void k_finish_gru(const float* __restrict__ acc, const float* __restrict__ den,
                             const float* __restrict__ bias,
                             const float* __restrict__ Wih0, const float* __restrict__ bih0,
                             const float* __restrict__ bhh0,
                             const float* __restrict__ Wih1, const float* __restrict__ bih1,
                             const float* __restrict__ bhh1,
                             float* __restrict__ out, int N)
{
    __shared__ float W0[3 * Hd][Hd + 1];
    __shared__ float W1[3 * Hd][Hd + 1];
    __shared__ float row[8][Hd];
    int tid = threadIdx.x;
    for (int i = tid; i < 3 * Hd * Hd; i += 256) {
        int r = i >> 5, c = i & 31;
        W0[r][c] = Wih0[i];
        W1[r][c] = Wih1[i];
    }
    int li = tid >> 5, j = tid & 31;
    int node = blockIdx.x * 8 + li;
    bool ok = node < N;
    float v = 0.f;
    if (ok) v = acc[(size_t)node * Hd + j] / den[node] + bias[j];
    row[li][j] = v;
    __syncthreads();
    // GRU0
    float gr = bih0[j], gz = bih0[Hd + j], gn = bih0[2 * Hd + j];
#pragma unroll
    for (int k = 0; k < Hd; k++) {
        float xv = row[li][k];
        gr += xv * W0[j][k];
        gz += xv * W0[Hd + j][k];
        gn += xv * W0[2 * Hd + j][k];
    }
    float r = 1.f / (1.f + expf(-(gr + bhh0[j])));
    float z = 1.f / (1.f + expf(-(gz + bhh0[Hd + j])));
    float n = tanhf(gn + r * bhh0[2 * Hd + j]);
    float o = (1.f - z) * n;
    __syncthreads();
    row[li][j] = o;
    __syncthreads();
    // GRU1
    gr = bih1[j]; gz = bih1[Hd + j]; gn = bih1[2 * Hd + j];
#pragma unroll
    for (int k = 0; k < Hd; k++) {
        float xv = row[li][k];
        gr += xv * W1[j][k];
        gz += xv * W1[Hd + j][k];
        gn += xv * W1[2 * Hd + j][k];
    }
    r = 1.f / (1.f + expf(-(gr + bhh1[j])));
    z = 1.f / (1.f + expf(-(gz + bhh1[Hd + j])));
    n = tanhf(gn + r * bhh1[2 * Hd + j]);
    if (ok) out[(size_t)node * Hd + j] = (1.f - z) * n;
}

// K5b: row = acc/denom + bias -> out = row @ lin_W.T + lin_b  (scalar per node)
__global__ void k_finish_lin(const float* __restrict__ acc, const float* __restrict__ den,
                             const float* __restrict__ bias,
                             const float* __restrict__ linW, const float* __restrict__ linb,
                             float* __restrict__ out, int N)
{
    int idx = blockIdx.x * 256 + threadIdx.x;
    int node = idx >> 5;
    if (node >= N) return;
    int j = idx & 31;
    float v = acc[(size_t)node * Hd + j] / den[node] + bias[j];
    float sacc = v * linW[j];
#pragma unroll
    for (int m = 16; m > 0; m >>= 1) sacc += __shfl_xor(sacc, m, 32);
    if (j == 0) out[node] = sacc + linb[0];
}

extern "C" void kernel_launch(void* const* d_in, const int* in_sizes, int n_in,
                              void* d_out, int out_size, void* d_ws, size_t ws_size,
                              hipStream_t stream)
{
    const float* x    = (const float*)d_in[0];
    const int*   ei   = (const int*)d_in[1];
    const float* W    = (const float*)d_in[2];
    const float* atts = (const float*)d_in[3];
    const float* attd = (const float*)d_in[4];
    const float* bias = (const float*)d_in[5];
    const float* Wih0 = (const float*)d_in[6];
    const float* bih0 = (const float*)d_in[8];
    const float* bhh0 = (const float*)d_in[9];
    const float* Wih1 = (const float*)d_in[10];
    const float* bih1 = (const float*)d_in[12];
    const float* bhh1 = (const float*)d_in[13];
    const float* linW = (const float*)d_in[14];
    const float* linb = (const float*)d_in[15];

    int N = in_sizes[0] / Hd;
    int E = in_sizes[1] / 2;
    const int* src = ei;
    const int* dst = ei + E;

    // workspace carve (all fully rewritten every launch before any read)
    float* h   = (float*)d_ws;                   // [N,32]
    float* h2  = h  + (size_t)N * Hd;            // [N,32]
    float* acc = h2 + (size_t)N * Hd;            // [N,32]
    float* as_ = acc + (size_t)N * Hd;           // [N]
    float* ad_ = as_ + N;                        // [N]
    float* den = ad_ + N;                        // [N]
    unsigned* menc = (unsigned*)(den + N);       // [N]
    float* e   = (float*)(menc + N);             // [E]

    dim3 blk(256);
    dim3 g_node8((N + 7) / 8);
    dim3 g_edge((E + 255) / 256);
    dim3 g_nf((N * Hd + 255) / 256);
    dim3 g_ef((unsigned)(((long long)E * Hd + 255) / 256));

    // ---- GAT pass 1 (input = relu(x)) ----
    hipLaunchKernelGGL((k_node_proj<true>), g_node8, blk, 0, stream, x, W, atts, attd, h, as_, ad_, menc, N);
    hipLaunchKernelGGL(k_edge_max, g_edge, blk, 0, stream, src, dst, as_, ad_, e, menc, E);
    hipLaunchKernelGGL(k_node_init, g_nf, blk, 0, stream, h, as_, ad_, menc, den, acc, N);
    hipLaunchKernelGGL(k_edge_scatter, g_ef, blk, 0, stream, src, dst, e, menc, h, den, acc, E);
    hipLaunchKernelGGL(k_finish_gru, g_node8, blk, 0, stream, acc, den, bias,
                       Wih0, bih0, bhh0, Wih1, bih1, bhh1, h2, N);

    // ---- GAT pass 2 (input = h2, no relu) ----
    hipLaunchKernelGGL((k_node_proj<false>), g_node8, blk, 0, stream, h2, W, atts, attd, h, as_, ad_, menc, N);
    hipLaunchKernelGGL(k_edge_max, g_edge, blk, 0, stream, src, dst, as_, ad_, e, menc, E);
    hipLaunchKernelGGL(k_node_init, g_nf, blk, 0, stream, h, as_, ad_, menc, den, acc, N);
    hipLaunchKernelGGL(k_edge_scatter, g_ef, blk, 0, stream, src, dst, e, menc, h, den, acc, E);
    hipLaunchKernelGGL(k_finish_lin, g_nf, blk, 0, stream, acc, den, bias, linW, linb, (float*)d_out, N);
}

// Round 2
// 614.658 us; speedup vs baseline: 1.7754x; 1.7754x over previous
//
#include <hip/hip_runtime.h>
#include <math.h>

#define Hd 32
#define NEG 0.2f

__device__ __forceinline__ float lrelu(float x) { return x > 0.f ? x : NEG * x; }

// ---------- CSR build (graph is identical for both GAT passes; built once) ----------

__global__ void k_hist(const int* __restrict__ dst, int* __restrict__ cnt, int E)
{
    int i = blockIdx.x * 256 + threadIdx.x;
    if (i < E) atomicAdd(&cnt[dst[i]], 1);
}

__global__ void k_scan1(const int* __restrict__ cnt, int* __restrict__ bsum, int N)
{
    __shared__ int sd[256];
    int t = threadIdx.x;
    int i = blockIdx.x * 256 + t;
    sd[t] = (i < N) ? cnt[i] : 0;
    __syncthreads();
    for (int s = 128; s > 0; s >>= 1) {
        if (t < s) sd[t] += sd[t + s];
        __syncthreads();
    }
    if (t == 0) bsum[blockIdx.x] = sd[0];
}

__global__ void k_scan2(int* __restrict__ bsum, int nb)
{
    __shared__ int sd[512];
    int t = threadIdx.x;
    int v = (t < nb) ? bsum[t] : 0;
    sd[t] = v;
    __syncthreads();
    for (int o = 1; o < 512; o <<= 1) {
        int x = (t >= o) ? sd[t - o] : 0;
        __syncthreads();
        sd[t] += x;
        __syncthreads();
    }
    if (t < nb) bsum[t] = sd[t] - v;   // exclusive
}

__global__ void k_scan3(const int* __restrict__ cnt, const int* __restrict__ bsum,
                        int* __restrict__ off, int N)
{
    __shared__ int sd[256];
    int t = threadIdx.x;
    int i = blockIdx.x * 256 + t;
    int v = (i < N) ? cnt[i] : 0;
    sd[t] = v;
    __syncthreads();
    for (int o = 1; o < 256; o <<= 1) {
        int x = (t >= o) ? sd[t - o] : 0;
        __syncthreads();
        sd[t] += x;
        __syncthreads();
    }
    if (i < N) off[i] = bsum[blockIdx.x] + sd[t] - v;   // exclusive start
}

// After k_fill, off[n] has been advanced to the END of node n's range.
__global__ void k_fill(const int* __restrict__ src, const int* __restrict__ dst,
                       int* __restrict__ off, int* __restrict__ csr_src, int E)
{
    int i = blockIdx.x * 256 + threadIdx.x;
    if (i >= E) return;
    int pos = atomicAdd(&off[dst[i]], 1);
    csr_src[pos] = src[i];
}

// ---------- per-pass kernels ----------

// h = act(x) @ W.T ; a_s = h@att_src ; a_d = h@att_dst
template<bool RELU>
__global__ void k_node_proj(const float* __restrict__ x, const float* __restrict__ W,
                            const float* __restrict__ att_s, const float* __restrict__ att_d,
                            float* __restrict__ h, float* __restrict__ as_, float* __restrict__ ad_,
                            int N)
{
    __shared__ float Wl[Hd][Hd + 1];
    __shared__ float xr[8][Hd];
    int tid = threadIdx.x;
    for (int i = tid; i < Hd * Hd; i += 256) Wl[i >> 5][i & 31] = W[i];
    int li = tid >> 5, j = tid & 31;
    int node = blockIdx.x * 8 + li;
    float v = 0.f;
    if (node < N) v = x[(size_t)node * Hd + j];
    if (RELU) v = fmaxf(v, 0.f);
    xr[li][j] = v;
    __syncthreads();
    if (node >= N) return;
    float a = 0.f;
#pragma unroll
    for (int k = 0; k < Hd; k++) a += xr[li][k] * Wl[j][k];
    h[(size_t)node * Hd + j] = a;
    float s = a * att_s[j], d = a * att_d[j];
#pragma unroll
    for (int m = 16; m > 0; m >>= 1) { s += __shfl_xor(s, m, 32); d += __shfl_xor(d, m, 32); }
    if (j == 0) { as_[node] = s; ad_[node] = d; }
}

// One 32-lane group per dst node. Sweep 1: segment max (edge-parallel).
// Sweep 2: scores edge-parallel, then shfl-broadcast (p,src) while all 32 lanes
// accumulate p*h[src][j] in registers. Epilogue: normalize + bias. No atomics.
__global__ void k_gather(const float* __restrict__ h, const float* __restrict__ as_,
                         const float* __restrict__ ad_, const int* __restrict__ cnt,
                         const int* __restrict__ off_end, const int* __restrict__ csr_src,
                         const float* __restrict__ bias, float* __restrict__ out, int N)
{
    int idx = blockIdx.x * 256 + threadIdx.x;
    int n = idx >> 5;
    if (n >= N) return;
    int j = idx & 31;
    int end = off_end[n], deg = cnt[n], beg = end - deg;
    float adn = ad_[n];
    float self_sc = lrelu(as_[n] + adn);

    // sweep 1: max
    float m = self_sc;
    for (int k = beg + j; k < end; k += 32)
        m = fmaxf(m, lrelu(as_[csr_src[k]] + adn));
#pragma unroll
    for (int o = 16; o > 0; o >>= 1) m = fmaxf(m, __shfl_xor(m, o, 32));

    // sweep 2: accumulate
    float denp = 0.f;   // lane-partial sum of p
    float accj = 0.f;
    for (int e0 = beg; e0 < end; e0 += 32) {
        int k = e0 + j;
        int sj = 0; float pj = 0.f;
        if (k < end) { sj = csr_src[k]; pj = expf(lrelu(as_[sj] + adn) - m); }
        denp += pj;
        int nv = min(32, end - e0);
        for (int t = 0; t < nv; t++) {
            float p = __shfl(pj, t, 32);
            int   s = __shfl(sj, t, 32);
            accj = fmaf(p, h[(size_t)s * Hd + j], accj);
        }
    }
#pragma unroll
    for (int o = 16; o > 0; o >>= 1) denp += __shfl_xor(denp, o, 32);
    float pself = expf(self_sc - m);
    float den = denp + pself;
    accj += pself * h[(size_t)n * Hd + j];
    out[(size_t)n * Hd + j] = accj / den + bias[j];
}

// gat -> GRU0 -> GRU1 (h_prev = 0, so gh = bhh)
__global__ void k_finish_gru(const float* __restrict__ gat,
                             const float* __restrict__ Wih0, const float* __restrict__ bih0,
                             const float* __restrict__ bhh0,
                             const float* __restrict__ Wih1, const float* __restrict__ bih1,
                             const float* __restrict__ bhh1,
                             float* __restrict__ out, int N)
{
    __shared__ float W0[3 * Hd][Hd + 1];
    __shared__ float W1[3 * Hd][Hd + 1];
    __shared__ float row[8][Hd];
    int tid = threadIdx.x;
    for (int i = tid; i < 3 * Hd * Hd; i += 256) {
        int r = i >> 5, c = i & 31;
        W0[r][c] = Wih0[i];
        W1[r][c] = Wih1[i];
    }
    int li = tid >> 5, j = tid & 31;
    int node = blockIdx.x * 8 + li;
    bool ok = node < N;
    float v = ok ? gat[(size_t)node * Hd + j] : 0.f;
    row[li][j] = v;
    __syncthreads();
    float gr = bih0[j], gz = bih0[Hd + j], gn = bih0[2 * Hd + j];
#pragma unroll
    for (int k = 0; k < Hd; k++) {
        float xv = row[li][k];
        gr += xv * W0[j][k];
        gz += xv * W0[Hd + j][k];
        gn += xv * W0[2 * Hd + j][k];
    }
    float r = 1.f / (1.f + expf(-(gr + bhh0[j])));
    float z = 1.f / (1.f + expf(-(gz + bhh0[Hd + j])));
    float nn = tanhf(gn + r * bhh0[2 * Hd + j]);
    float o = (1.f - z) * nn;
    __syncthreads();
    row[li][j] = o;
    __syncthreads();
    gr = bih1[j]; gz = bih1[Hd + j]; gn = bih1[2 * Hd + j];
#pragma unroll
    for (int k = 0; k < Hd; k++) {
        float xv = row[li][k];
        gr += xv * W1[j][k];
        gz += xv * W1[Hd + j][k];
        gn += xv * W1[2 * Hd + j][k];
    }
    r = 1.f / (1.f + expf(-(gr + bhh1[j])));
    z = 1.f / (1.f + expf(-(gz + bhh1[Hd + j])));
    nn = tanhf(gn + r * bhh1[2 * Hd + j]);
    if (ok) out[(size_t)node * Hd + j] = (1.f - z) * nn;
}

// gat -> out = gat @ lin_W.T + lin_b
__global__ void k_finish_lin(const float* __restrict__ gat,
                             const float* __restrict__ linW, const float* __restrict__ linb,
                             float* __restrict__ out, int N)
{
    int idx = blockIdx.x * 256 + threadIdx.x;
    int node = idx >> 5;
    if (node >= N) return;
    int j = idx & 31;
    float sacc = gat[(size_t)node * Hd + j] * linW[j];
#pragma unroll
    for (int m = 16; m > 0; m >>= 1) sacc += __shfl_xor(sacc, m, 32);
    if (j == 0) out[node] = sacc + linb[0];
}

extern "C" void kernel_launch(void* const* d_in, const int* in_sizes, int n_in,
                              void* d_out, int out_size, void* d_ws, size_t ws_size,
                              hipStream_t stream)
{
    const float* x    = (const float*)d_in[0];
    const int*   ei   = (const int*)d_in[1];
    const float* W    = (const float*)d_in[2];
    const float* atts = (const float*)d_in[3];
    const float* attd = (const float*)d_in[4];
    const float* bias = (const float*)d_in[5];
    const float* Wih0 = (const float*)d_in[6];
    const float* bih0 = (const float*)d_in[8];
    const float* bhh0 = (const float*)d_in[9];
    const float* Wih1 = (const float*)d_in[10];
    const float* bih1 = (const float*)d_in[12];
    const float* bhh1 = (const float*)d_in[13];
    const float* linW = (const float*)d_in[14];
    const float* linb = (const float*)d_in[15];

    int N = in_sizes[0] / Hd;
    int E = in_sizes[1] / 2;
    const int* src = ei;
    const int* dst = ei + E;

    // workspace carve (every slot rewritten before any read, each launch)
    float* h    = (float*)d_ws;                  // [N,32]
    float* gat  = h   + (size_t)N * Hd;          // [N,32]
    float* h2   = gat + (size_t)N * Hd;          // [N,32]
    float* as_  = h2  + (size_t)N * Hd;          // [N]
    float* ad_  = as_ + N;                       // [N]
    int*   cnt  = (int*)(ad_ + N);               // [N]
    int*   off  = cnt + N;                       // [N] (becomes end-offsets after k_fill)
    int*   bsum = off + N;                       // [nb]
    int*   csr  = bsum + 1024;                   // [E]

    dim3 blk(256);
    int nb = (N + 255) / 256;
    dim3 g_node8((N + 7) / 8);
    dim3 g_edge((E + 255) / 256);
    dim3 g_nf((N * Hd + 255) / 256);

    // ---- CSR build (once; shared by both GAT passes) ----
    hipMemsetAsync(cnt, 0, (size_t)N * sizeof(int), stream);
    hipLaunchKernelGGL(k_hist, g_edge, blk, 0, stream, dst, cnt, E);
    hipLaunchKernelGGL(k_scan1, dim3(nb), blk, 0, stream, cnt, bsum, N);
    hipLaunchKernelGGL(k_scan2, dim3(1), dim3(512), 0, stream, bsum, nb);
    hipLaunchKernelGGL(k_scan3, dim3(nb), blk, 0, stream, cnt, bsum, off, N);
    hipLaunchKernelGGL(k_fill, g_edge, blk, 0, stream, src, dst, off, csr, E);

    // ---- GAT pass 1 (input = relu(x)) + GRU0 + GRU1 ----
    hipLaunchKernelGGL((k_node_proj<true>), g_node8, blk, 0, stream, x, W, atts, attd, h, as_, ad_, N);
    hipLaunchKernelGGL(k_gather, g_nf, blk, 0, stream, h, as_, ad_, cnt, off, csr, bias, gat, N);
    hipLaunchKernelGGL(k_finish_gru, g_node8, blk, 0, stream, gat,
                       Wih0, bih0, bhh0, Wih1, bih1, bhh1, h2, N);

    // ---- GAT pass 2 (input = h2) + linear ----
    hipLaunchKernelGGL((k_node_proj<false>), g_node8, blk, 0, stream, h2, W, atts, attd, h, as_, ad_, N);
    hipLaunchKernelGGL(k_gather, g_nf, blk, 0, stream, h, as_, ad_, cnt, off, csr, bias, gat, N);
    hipLaunchKernelGGL(k_finish_lin, g_nf, blk, 0, stream, gat, linW, linb, (float*)d_out, N);
}

// Round 3
// 565.069 us; speedup vs baseline: 1.9312x; 1.0878x over previous
//
#include <hip/hip_runtime.h>
#include <math.h>

#define Hd 32
#define NEG 0.2f
#define BSH 6                 // 64 nodes per bucket
#define BNODES (1 << BSH)

__device__ __forceinline__ float lrelu(float x) { return x > 0.f ? x : NEG * x; }

// ---------- CSR build ----------

__global__ void k_hist(const int* __restrict__ dst, int* __restrict__ cnt, int E)
{
    int i = blockIdx.x * 256 + threadIdx.x;
    if (i < E) atomicAdd(&cnt[dst[i]], 1);
}

__global__ void k_scan1(const int* __restrict__ cnt, int* __restrict__ bsum, int N)
{
    __shared__ int sd[256];
    int t = threadIdx.x;
    int i = blockIdx.x * 256 + t;
    sd[t] = (i < N) ? cnt[i] : 0;
    __syncthreads();
    for (int s = 128; s > 0; s >>= 1) {
        if (t < s) sd[t] += sd[t + s];
        __syncthreads();
    }
    if (t == 0) bsum[blockIdx.x] = sd[0];
}

__global__ void k_scan2(int* __restrict__ bsum, int nb)
{
    __shared__ int sd[512];
    int t = threadIdx.x;
    int v = (t < nb) ? bsum[t] : 0;
    sd[t] = v;
    __syncthreads();
    for (int o = 1; o < 512; o <<= 1) {
        int x = (t >= o) ? sd[t - o] : 0;
        __syncthreads();
        sd[t] += x;
        __syncthreads();
    }
    if (t < nb) bsum[t] = sd[t] - v;   // exclusive
}

__global__ void k_scan3(const int* __restrict__ cnt, const int* __restrict__ bsum,
                        int* __restrict__ off, int N)
{
    __shared__ int sd[256];
    int t = threadIdx.x;
    int i = blockIdx.x * 256 + t;
    int v = (i < N) ? cnt[i] : 0;
    sd[t] = v;
    __syncthreads();
    for (int o = 1; o < 256; o <<= 1) {
        int x = (t >= o) ? sd[t - o] : 0;
        __syncthreads();
        sd[t] += x;
        __syncthreads();
    }
    if (i < N) off[i] = bsum[blockIdx.x] + sd[t] - v;   // exclusive start
}

// bucket cursors, padded one per 64B line
__global__ void k_bcur_init(const int* __restrict__ off, int* __restrict__ bcur, int nbuck)
{
    int b = blockIdx.x * 256 + threadIdx.x;
    if (b < nbuck) bcur[b * 16] = off[b << BSH];
}

// Pass A: append (dst&63, src) packed u32 into the dst-bucket's contiguous slice.
// Writes stream at nbuck rolling pointers -> cache lines fill sequentially.
__global__ void k_bucket(const int* __restrict__ src, const int* __restrict__ dst,
                         int* __restrict__ bcur, unsigned* __restrict__ tmp, int E)
{
    int i = blockIdx.x * 256 + threadIdx.x;
    if (i >= E) return;
    int d = dst[i], s = src[i];
    int pos = atomicAdd(&bcur[(d >> BSH) * 16], 1);
    tmp[pos] = ((unsigned)(d & (BNODES - 1)) << 17) | (unsigned)s;
}

// Pass B: one block per bucket; 64 per-node cursors in LDS; csr writes land in a
// small L2-resident window so lines coalesce fully.
__global__ void k_place(const unsigned* __restrict__ tmp, const int* __restrict__ off,
                        int* __restrict__ csr, int N, int E)
{
    __shared__ int cur[BNODES];
    int b = blockIdx.x;
    int t = threadIdx.x;
    int base = b << BSH;
    if (t < BNODES) {
        int node = base + t;
        cur[t] = (node < N) ? off[node] : E;
    }
    __syncthreads();
    int bstart = off[base];
    int bend = (base + BNODES < N) ? off[base + BNODES] : E;
    for (int k = bstart + t; k < bend; k += 256) {
        unsigned v = tmp[k];
        int pos = atomicAdd(&cur[v >> 17], 1);
        csr[pos] = (int)(v & 0x1FFFFu);
    }
}

// ---------- per-pass kernels ----------

template<bool RELU>
__global__ void k_node_proj(const float* __restrict__ x, const float* __restrict__ W,
                            const float* __restrict__ att_s, const float* __restrict__ att_d,
                            float* __restrict__ h, float* __restrict__ as_, float* __restrict__ ad_,
                            int N)
{
    __shared__ float Wl[Hd][Hd + 1];
    __shared__ float xr[8][Hd];
    int tid = threadIdx.x;
    for (int i = tid; i < Hd * Hd; i += 256) Wl[i >> 5][i & 31] = W[i];
    int li = tid >> 5, j = tid & 31;
    int node = blockIdx.x * 8 + li;
    float v = 0.f;
    if (node < N) v = x[(size_t)node * Hd + j];
    if (RELU) v = fmaxf(v, 0.f);
    xr[li][j] = v;
    __syncthreads();
    if (node >= N) return;
    float a = 0.f;
#pragma unroll
    for (int k = 0; k < Hd; k++) a += xr[li][k] * Wl[j][k];
    h[(size_t)node * Hd + j] = a;
    float s = a * att_s[j], d = a * att_d[j];
#pragma unroll
    for (int m = 16; m > 0; m >>= 1) { s += __shfl_xor(s, m, 32); d += __shfl_xor(d, m, 32); }
    if (j == 0) { as_[node] = s; ad_[node] = d; }
}

// One 32-lane group per dst node; two sweeps (max, accumulate); no atomics.
__global__ void k_gather(const float* __restrict__ h, const float* __restrict__ as_,
                         const float* __restrict__ ad_, const int* __restrict__ cnt,
                         const int* __restrict__ off, const int* __restrict__ csr_src,
                         const float* __restrict__ bias, float* __restrict__ out, int N)
{
    int idx = blockIdx.x * 256 + threadIdx.x;
    int n = idx >> 5;
    if (n >= N) return;
    int j = idx & 31;
    int beg = off[n], end = beg + cnt[n];
    float adn = ad_[n];
    float self_sc = lrelu(as_[n] + adn);

    float m = self_sc;
    for (int k = beg + j; k < end; k += 32)
        m = fmaxf(m, lrelu(as_[csr_src[k]] + adn));
#pragma unroll
    for (int o = 16; o > 0; o >>= 1) m = fmaxf(m, __shfl_xor(m, o, 32));

    float denp = 0.f;
    float accj = 0.f;
    for (int e0 = beg; e0 < end; e0 += 32) {
        int k = e0 + j;
        int sj = 0; float pj = 0.f;
        if (k < end) { sj = csr_src[k]; pj = expf(lrelu(as_[sj] + adn) - m); }
        denp += pj;
        int nv = min(32, end - e0);
        for (int t = 0; t < nv; t++) {
            float p = __shfl(pj, t, 32);
            int   s = __shfl(sj, t, 32);
            accj = fmaf(p, h[(size_t)s * Hd + j], accj);
        }
    }
#pragma unroll
    for (int o = 16; o > 0; o >>= 1) denp += __shfl_xor(denp, o, 32);
    float pself = expf(self_sc - m);
    float den = denp + pself;
    accj += pself * h[(size_t)n * Hd + j];
    out[(size_t)n * Hd + j] = accj / den + bias[j];
}

__global__ void k_finish_gru(const float* __restrict__ gat,
                             const float* __restrict__ Wih0, const float* __restrict__ bih0,
                             const float* __restrict__ bhh0,
                             const float* __restrict__ Wih1, const float* __restrict__ bih1,
                             const float* __restrict__ bhh1,
                             float* __restrict__ out, int N)
{
    __shared__ float W0[3 * Hd][Hd + 1];
    __shared__ float W1[3 * Hd][Hd + 1];
    __shared__ float row[8][Hd];
    int tid = threadIdx.x;
    for (int i = tid; i < 3 * Hd * Hd; i += 256) {
        int r = i >> 5, c = i & 31;
        W0[r][c] = Wih0[i];
        W1[r][c] = Wih1[i];
    }
    int li = tid >> 5, j = tid & 31;
    int node = blockIdx.x * 8 + li;
    bool ok = node < N;
    float v = ok ? gat[(size_t)node * Hd + j] : 0.f;
    row[li][j] = v;
    __syncthreads();
    float gr = bih0[j], gz = bih0[Hd + j], gn = bih0[2 * Hd + j];
#pragma unroll
    for (int k = 0; k < Hd; k++) {
        float xv = row[li][k];
        gr += xv * W0[j][k];
        gz += xv * W0[Hd + j][k];
        gn += xv * W0[2 * Hd + j][k];
    }
    float r = 1.f / (1.f + expf(-(gr + bhh0[j])));
    float z = 1.f / (1.f + expf(-(gz + bhh0[Hd + j])));
    float nn = tanhf(gn + r * bhh0[2 * Hd + j]);
    float o = (1.f - z) * nn;
    __syncthreads();
    row[li][j] = o;
    __syncthreads();
    gr = bih1[j]; gz = bih1[Hd + j]; gn = bih1[2 * Hd + j];
#pragma unroll
    for (int k = 0; k < Hd; k++) {
        float xv = row[li][k];
        gr += xv * W1[j][k];
        gz += xv * W1[Hd + j][k];
        gn += xv * W1[2 * Hd + j][k];
    }
    r = 1.f / (1.f + expf(-(gr + bhh1[j])));
    z = 1.f / (1.f + expf(-(gz + bhh1[Hd + j])));
    nn = tanhf(gn + r * bhh1[2 * Hd + j]);
    if (ok) out[(size_t)node * Hd + j] = (1.f - z) * nn;
}

__global__ void k_finish_lin(const float* __restrict__ gat,
                             const float* __restrict__ linW, const float* __restrict__ linb,
                             float* __restrict__ out, int N)
{
    int idx = blockIdx.x * 256 + threadIdx.x;
    int node = idx >> 5;
    if (node >= N) return;
    int j = idx & 31;
    float sacc = gat[(size_t)node * Hd + j] * linW[j];
#pragma unroll
    for (int m = 16; m > 0; m >>= 1) sacc += __shfl_xor(sacc, m, 32);
    if (j == 0) out[node] = sacc + linb[0];
}

extern "C" void kernel_launch(void* const* d_in, const int* in_sizes, int n_in,
                              void* d_out, int out_size, void* d_ws, size_t ws_size,
                              hipStream_t stream)
{
    const float* x    = (const float*)d_in[0];
    const int*   ei   = (const int*)d_in[1];
    const float* W    = (const float*)d_in[2];
    const float* atts = (const float*)d_in[3];
    const float* attd = (const float*)d_in[4];
    const float* bias = (const float*)d_in[5];
    const float* Wih0 = (const float*)d_in[6];
    const float* bih0 = (const float*)d_in[8];
    const float* bhh0 = (const float*)d_in[9];
    const float* Wih1 = (const float*)d_in[10];
    const float* bih1 = (const float*)d_in[12];
    const float* bhh1 = (const float*)d_in[13];
    const float* linW = (const float*)d_in[14];
    const float* linb = (const float*)d_in[15];

    int N = in_sizes[0] / Hd;
    int E = in_sizes[1] / 2;
    const int* src = ei;
    const int* dst = ei + E;
    int nbuck = (N + BNODES - 1) >> BSH;

    // workspace carve (every slot rewritten before any read, each launch)
    float* h    = (float*)d_ws;                  // [N,32]
    float* gat  = h   + (size_t)N * Hd;          // [N,32]  (tmp aliases this during CSR build)
    float* h2   = gat + (size_t)N * Hd;          // [N,32]
    float* as_  = h2  + (size_t)N * Hd;          // [N]
    float* ad_  = as_ + N;                       // [N]
    int*   cnt  = (int*)(ad_ + N);               // [N]
    int*   off  = cnt + N;                       // [N] exclusive start offsets
    int*   bsum = off + N;                       // [<=512]
    int*   bcur = bsum + 1024;                   // [nbuck*16] padded cursors
    int*   csr  = bcur + (size_t)nbuck * 16;     // [E]
    unsigned* tmp = (unsigned*)gat;              // [E] aliases gat (disjoint lifetime)

    dim3 blk(256);
    int nb = (N + 255) / 256;
    dim3 g_node8((N + 7) / 8);
    dim3 g_edge((E + 255) / 256);
    dim3 g_nf((N * Hd + 255) / 256);

    // ---- CSR build (once; shared by both GAT passes) ----
    hipMemsetAsync(cnt, 0, (size_t)N * sizeof(int), stream);
    hipLaunchKernelGGL(k_hist, g_edge, blk, 0, stream, dst, cnt, E);
    hipLaunchKernelGGL(k_scan1, dim3(nb), blk, 0, stream, cnt, bsum, N);
    hipLaunchKernelGGL(k_scan2, dim3(1), dim3(512), 0, stream, bsum, nb);
    hipLaunchKernelGGL(k_scan3, dim3(nb), blk, 0, stream, cnt, bsum, off, N);
    hipLaunchKernelGGL(k_bcur_init, dim3((nbuck + 255) / 256), blk, 0, stream, off, bcur, nbuck);
    hipLaunchKernelGGL(k_bucket, g_edge, blk, 0, stream, src, dst, bcur, tmp, E);
    hipLaunchKernelGGL(k_place, dim3(nbuck), blk, 0, stream, tmp, off, csr, N, E);

    // ---- GAT pass 1 (input = relu(x)) + GRU0 + GRU1 ----
    hipLaunchKernelGGL((k_node_proj<true>), g_node8, blk, 0, stream, x, W, atts, attd, h, as_, ad_, N);
    hipLaunchKernelGGL(k_gather, g_nf, blk, 0, stream, h, as_, ad_, cnt, off, csr, bias, gat, N);
    hipLaunchKernelGGL(k_finish_gru, g_node8, blk, 0, stream, gat,
                       Wih0, bih0, bhh0, Wih1, bih1, bhh1, h2, N);

    // ---- GAT pass 2 (input = h2) + linear ----
    hipLaunchKernelGGL((k_node_proj<false>), g_node8, blk, 0, stream, h2, W, atts, attd, h, as_, ad_, N);
    hipLaunchKernelGGL(k_gather, g_nf, blk, 0, stream, h, as_, ad_, cnt, off, csr, bias, gat, N);
    hipLaunchKernelGGL(k_finish_lin, g_nf, blk, 0, stream, gat, linW, linb, (float*)d_out, N);
}

// Round 5
// 377.862 us; speedup vs baseline: 2.8880x; 1.4954x over previous
//
#include <hip/hip_runtime.h>
#include <math.h>

#define Hd 32
#define NEG 0.2f
#define BSH 9                  // 512 nodes per bucket
#define BN (1 << BSH)
#define CHUNK 8192
#define NBUCK_MAX 256

__device__ __forceinline__ float lrelu(float x) { return x > 0.f ? x : NEG * x; }

// ---------- CSR build: chunk x bucket counting sort (no global atomics) ----------

// per-chunk LDS histogram over buckets -> counts[b * nchunk + c]  (bucket-major)
__global__ void k_histb(const int* __restrict__ dst, int* __restrict__ counts,
                        int E, int nchunk, int nbuck)
{
    __shared__ int hh[NBUCK_MAX];
    int c = blockIdx.x, t = threadIdx.x;
    for (int i = t; i < nbuck; i += 256) hh[i] = 0;
    __syncthreads();
    int beg = c * CHUNK, end = min(beg + CHUNK, E);
    for (int k = beg + t; k < end; k += 256) atomicAdd(&hh[dst[k] >> BSH], 1);
    __syncthreads();
    for (int i = t; i < nbuck; i += 256) counts[i * nchunk + c] = hh[i];
}

// generic 3-level exclusive scan over length L (L <= 512*256)
__global__ void k_scan1(const int* __restrict__ in, int* __restrict__ bsum, int L)
{
    __shared__ int sd[256];
    int t = threadIdx.x;
    int i = blockIdx.x * 256 + t;
    sd[t] = (i < L) ? in[i] : 0;
    __syncthreads();
    for (int s = 128; s > 0; s >>= 1) {
        if (t < s) sd[t] += sd[t + s];
        __syncthreads();
    }
    if (t == 0) bsum[blockIdx.x] = sd[0];
}

__global__ void k_scan2(int* __restrict__ bsum, int nb)
{
    __shared__ int sd[512];
    int t = threadIdx.x;
    int v = (t < nb) ? bsum[t] : 0;
    sd[t] = v;
    __syncthreads();
    for (int o = 1; o < 512; o <<= 1) {
        int x = (t >= o) ? sd[t - o] : 0;
        __syncthreads();
        sd[t] += x;
        __syncthreads();
    }
    if (t < nb) bsum[t] = sd[t] - v;   // exclusive
}

__global__ void k_scan3(const int* __restrict__ in, const int* __restrict__ bsum,
                        int* __restrict__ out, int L)
{
    __shared__ int sd[256];
    int t = threadIdx.x;
    int i = blockIdx.x * 256 + t;
    int v = (i < L) ? in[i] : 0;
    sd[t] = v;
    __syncthreads();
    for (int o = 1; o < 256; o <<= 1) {
        int x = (t >= o) ? sd[t - o] : 0;
        __syncthreads();
        sd[t] += x;
        __syncthreads();
    }
    if (i < L) out[i] = bsum[blockIdx.x] + sd[t] - v;   // exclusive
}

// chunk re-read; LDS cursors seeded from cstart; coalesced segment writes, no global atomics
__global__ void k_scatterb(const int* __restrict__ src, const int* __restrict__ dst,
                           const int* __restrict__ cstart, unsigned* __restrict__ tmp,
                           int E, int nchunk, int nbuck)
{
    __shared__ int cur[NBUCK_MAX];
    int c = blockIdx.x, t = threadIdx.x;
    for (int i = t; i < nbuck; i += 256) cur[i] = cstart[i * nchunk + c];
    __syncthreads();
    int beg = c * CHUNK, end = min(beg + CHUNK, E);
    for (int k = beg + t; k < end; k += 256) {
        int d = dst[k];
        int pos = atomicAdd(&cur[d >> BSH], 1);
        tmp[pos] = ((unsigned)(d & (BN - 1)) << 17) | (unsigned)src[k];
    }
}

// one block per bucket: per-node counts+offsets (LDS scan) -> off/cnt globals; place csr
__global__ void k_place2(const unsigned* __restrict__ tmp, const int* __restrict__ cstart,
                         int* __restrict__ csr, int* __restrict__ off_g, int* __restrict__ cnt_g,
                         int N, int E, int nchunk, int nbuck)
{
    __shared__ int lcnt[BN];
    __shared__ int lscan[256];
    __shared__ int lcur[BN];
    int b = blockIdx.x, t = threadIdx.x;
    int bstart = cstart[b * nchunk];
    int bend = (b + 1 < nbuck) ? cstart[(b + 1) * nchunk] : E;
    lcnt[t] = 0; lcnt[t + 256] = 0;
    __syncthreads();
    for (int k = bstart + t; k < bend; k += 256)
        atomicAdd(&lcnt[tmp[k] >> 17], 1);
    __syncthreads();
    int c0 = lcnt[2 * t], c1 = lcnt[2 * t + 1];
    int pair = c0 + c1;
    lscan[t] = pair;
    __syncthreads();
    for (int o = 1; o < 256; o <<= 1) {
        int x = (t >= o) ? lscan[t - o] : 0;
        __syncthreads();
        lscan[t] += x;
        __syncthreads();
    }
    int excl = lscan[t] - pair;
    int base = b << BSH;
    int n0 = base + 2 * t, n1 = n0 + 1;
    int o0 = bstart + excl, o1 = o0 + c0;
    lcur[2 * t] = o0; lcur[2 * t + 1] = o1;
    if (n0 < N) { off_g[n0] = o0; cnt_g[n0] = c0; }
    if (n1 < N) { off_g[n1] = o1; cnt_g[n1] = c1; }
    __syncthreads();
    for (int k = bstart + t; k < bend; k += 256) {
        unsigned v = tmp[k];
        int pos = atomicAdd(&lcur[v >> 17], 1);
        csr[pos] = (int)(v & 0x1FFFFu);
    }
}

// ---------- per-pass kernels ----------

template<bool RELU>
__global__ void k_node_proj(const float* __restrict__ x, const float* __restrict__ W,
                            const float* __restrict__ att_s, const float* __restrict__ att_d,
                            float* __restrict__ h, float* __restrict__ as_, float* __restrict__ ad_,
                            int N)
{
    __shared__ float Wl[Hd][Hd + 1];
    __shared__ float xr[8][Hd];
    int tid = threadIdx.x;
    for (int i = tid; i < Hd * Hd; i += 256) Wl[i >> 5][i & 31] = W[i];
    int li = tid >> 5, j = tid & 31;
    int node = blockIdx.x * 8 + li;
    float v = 0.f;
    if (node < N) v = x[(size_t)node * Hd + j];
    if (RELU) v = fmaxf(v, 0.f);
    xr[li][j] = v;
    __syncthreads();
    if (node >= N) return;
    float a = 0.f;
#pragma unroll
    for (int k = 0; k < Hd; k++) a += xr[li][k] * Wl[j][k];
    h[(size_t)node * Hd + j] = a;
    float s = a * att_s[j], d = a * att_d[j];
#pragma unroll
    for (int m = 16; m > 0; m >>= 1) { s += __shfl_xor(s, m, 32); d += __shfl_xor(d, m, 32); }
    if (j == 0) { as_[node] = s; ad_[node] = d; }
}

// One 32-lane group per dst node; two sweeps (max, accumulate); no atomics.
__global__ void k_gather(const float* __restrict__ h, const float* __restrict__ as_,
                         const float* __restrict__ ad_, const int* __restrict__ cnt,
                         const int* __restrict__ off, const int* __restrict__ csr_src,
                         const float* __restrict__ bias, float* __restrict__ out, int N)
{
    int idx = blockIdx.x * 256 + threadIdx.x;
    int n = idx >> 5;
    if (n >= N) return;
    int j = idx & 31;
    int beg = off[n], end = beg + cnt[n];
    float adn = ad_[n];
    float self_sc = lrelu(as_[n] + adn);

    float m = self_sc;
    for (int k = beg + j; k < end; k += 32)
        m = fmaxf(m, lrelu(as_[csr_src[k]] + adn));
#pragma unroll
    for (int o = 16; o > 0; o >>= 1) m = fmaxf(m, __shfl_xor(m, o, 32));

    float denp = 0.f;
    float accj = 0.f;
    for (int e0 = beg; e0 < end; e0 += 32) {
        int k = e0 + j;
        int sj = 0; float pj = 0.f;
        if (k < end) { sj = csr_src[k]; pj = expf(lrelu(as_[sj] + adn) - m); }
        denp += pj;
        int nv = min(32, end - e0);
        for (int t = 0; t < nv; t++) {
            float p = __shfl(pj, t, 32);
            int   s = __shfl(sj, t, 32);
            accj = fmaf(p, h[(size_t)s * Hd + j], accj);
        }
    }
#pragma unroll
    for (int o = 16; o > 0; o >>= 1) denp += __shfl_xor(denp, o, 32);
    float pself = expf(self_sc - m);
    float den = denp + pself;
    accj += pself * h[(size_t)n * Hd + j];
    out[(size_t)n * Hd + j] = accj / den + bias[j];
}

__global__ void k_finish_gru(const float* __restrict__ gat,
                             const float* __restrict__ Wih0, const float* __restrict__ bih0,
                             const float* __restrict__ bhh0,
                             const float* __restrict__ Wih1, const float* __restrict__ bih1,
                             const float* __restrict__ bhh1,
                             float* __restrict__ out, int N)
{
    __shared__ float W0[3 * Hd][Hd + 1];
    __shared__ float W1[3 * Hd][Hd + 1];
    __shared__ float row[8][Hd];
    int tid = threadIdx.x;
    for (int i = tid; i < 3 * Hd * Hd; i += 256) {
        int r = i >> 5, c = i & 31;
        W0[r][c] = Wih0[i];
        W1[r][c] = Wih1[i];
    }
    int li = tid >> 5, j = tid & 31;
    int node = blockIdx.x * 8 + li;
    bool ok = node < N;
    float v = ok ? gat[(size_t)node * Hd + j] : 0.f;
    row[li][j] = v;
    __syncthreads();
    float gr = bih0[j], gz = bih0[Hd + j], gn = bih0[2 * Hd + j];
#pragma unroll
    for (int k = 0; k < Hd; k++) {
        float xv = row[li][k];
        gr += xv * W0[j][k];
        gz += xv * W0[Hd + j][k];
        gn += xv * W0[2 * Hd + j][k];
    }
    float r = 1.f / (1.f + expf(-(gr + bhh0[j])));
    float z = 1.f / (1.f + expf(-(gz + bhh0[Hd + j])));
    float nn = tanhf(gn + r * bhh0[2 * Hd + j]);
    float o = (1.f - z) * nn;
    __syncthreads();
    row[li][j] = o;
    __syncthreads();
    gr = bih1[j]; gz = bih1[Hd + j]; gn = bih1[2 * Hd + j];
#pragma unroll
    for (int k = 0; k < Hd; k++) {
        float xv = row[li][k];
        gr += xv * W1[j][k];
        gz += xv * W1[Hd + j][k];
        gn += xv * W1[2 * Hd + j][k];
    }
    r = 1.f / (1.f + expf(-(gr + bhh1[j])));
    z = 1.f / (1.f + expf(-(gz + bhh1[Hd + j])));
    nn = tanhf(gn + r * bhh1[2 * Hd + j]);
    if (ok) out[(size_t)node * Hd + j] = (1.f - z) * nn;
}

__global__ void k_finish_lin(const float* __restrict__ gat,
                             const float* __restrict__ linW, const float* __restrict__ linb,
                             float* __restrict__ out, int N)
{
    int idx = blockIdx.x * 256 + threadIdx.x;
    int node = idx >> 5;
    if (node >= N) return;
    int j = idx & 31;
    float sacc = gat[(size_t)node * Hd + j] * linW[j];
#pragma unroll
    for (int m = 16; m > 0; m >>= 1) sacc += __shfl_xor(sacc, m, 32);
    if (j == 0) out[node] = sacc + linb[0];
}

extern "C" void kernel_launch(void* const* d_in, const int* in_sizes, int n_in,
                              void* d_out, int out_size, void* d_ws, size_t ws_size,
                              hipStream_t stream)
{
    const float* x    = (const float*)d_in[0];
    const int*   ei   = (const int*)d_in[1];
    const float* W    = (const float*)d_in[2];
    const float* atts = (const float*)d_in[3];
    const float* attd = (const float*)d_in[4];
    const float* bias = (const float*)d_in[5];
    const float* Wih0 = (const float*)d_in[6];
    const float* bih0 = (const float*)d_in[8];
    const float* bhh0 = (const float*)d_in[9];
    const float* Wih1 = (const float*)d_in[10];
    const float* bih1 = (const float*)d_in[12];
    const float* bhh1 = (const float*)d_in[13];
    const float* linW = (const float*)d_in[14];
    const float* linb = (const float*)d_in[15];

    int N = in_sizes[0] / Hd;
    int E = in_sizes[1] / 2;
    const int* src = ei;
    const int* dst = ei + E;
    int nbuck = (N + BN - 1) >> BSH;          // 196 for N=100000
    int nchunk = (E + CHUNK - 1) / CHUNK;     // 293 for E=2.4M
    int L = nbuck * nchunk;                   // 57428
    int nbL = (L + 255) / 256;                // 225 (<=512)

    // workspace carve (every slot rewritten before any read, each launch)
    float* h     = (float*)d_ws;                 // [N,32]
    float* gat   = h   + (size_t)N * Hd;         // [N,32]  (tmp aliases this)
    float* h2    = gat + (size_t)N * Hd;         // [N,32]
    float* as_   = h2  + (size_t)N * Hd;         // [N]
    float* ad_   = as_ + N;                      // [N]
    int*   cnt   = (int*)(ad_ + N);              // [N]
    int*   off   = cnt + N;                      // [N]
    int*   counts= off + N;                      // [L]
    int*   cstart= counts + L;                   // [L]
    int*   bsum  = cstart + L;                   // [512]
    int*   csr   = bsum + 512;                   // [E]
    unsigned* tmp = (unsigned*)gat;              // [E] aliases gat (disjoint lifetime)

    dim3 blk(256);
    dim3 g_node8((N + 7) / 8);
    dim3 g_nf((N * Hd + 255) / 256);

    // ---- CSR build (once; shared by both GAT passes) ----
    hipLaunchKernelGGL(k_histb, dim3(nchunk), blk, 0, stream, dst, counts, E, nchunk, nbuck);
    hipLaunchKernelGGL(k_scan1, dim3(nbL), blk, 0, stream, counts, bsum, L);
    hipLaunchKernelGGL(k_scan2, dim3(1), dim3(512), 0, stream, bsum, nbL);
    hipLaunchKernelGGL(k_scan3, dim3(nbL), blk, 0, stream, counts, bsum, cstart, L);
    hipLaunchKernelGGL(k_scatterb, dim3(nchunk), blk, 0, stream, src, dst, cstart, tmp, E, nchunk, nbuck);
    hipLaunchKernelGGL(k_place2, dim3(nbuck), blk, 0, stream, tmp, cstart, csr, off, cnt, N, E, nchunk, nbuck);

    // ---- GAT pass 1 (input = relu(x)) + GRU0 + GRU1 ----
    hipLaunchKernelGGL((k_node_proj<true>), g_node8, blk, 0, stream, x, W, atts, attd, h, as_, ad_, N);
    hipLaunchKernelGGL(k_gather, g_nf, blk, 0, stream, h, as_, ad_, cnt, off, csr, bias, gat, N);
    hipLaunchKernelGGL(k_finish_gru, g_node8, blk, 0, stream, gat,
                       Wih0, bih0, bhh0, Wih1, bih1, bhh1, h2, N);

    // ---- GAT pass 2 (input = h2) + linear ----
    hipLaunchKernelGGL((k_node_proj<false>), g_node8, blk, 0, stream, h2, W, atts, attd, h, as_, ad_, N);
    hipLaunchKernelGGL(k_gather, g_nf, blk, 0, stream, h, as_, ad_, cnt, off, csr, bias, gat, N);
    hipLaunchKernelGGL(k_finish_lin, g_nf, blk, 0, stream, gat, linW, linb, (float*)d_out, N);
}

// Round 7
// 272.513 us; speedup vs baseline: 4.0045x; 1.3866x over previous
//
#include <hip/hip_runtime.h>
#include <math.h>

#define Hd 32
#define NEG 0.2f
#define BSH 9                  // 512 nodes per bucket
#define BN (1 << BSH)
#define CHUNK 8192
#define NBUCK_MAX 256

__device__ __forceinline__ float lrelu(float x) { return x > 0.f ? x : NEG * x; }

// ---------- CSR build: chunk x bucket counting sort (no global atomics) ----------

__global__ void k_histb(const int* __restrict__ dst, int* __restrict__ counts,
                        int E, int nchunk, int nbuck)
{
    __shared__ int hh[NBUCK_MAX];
    int c = blockIdx.x, t = threadIdx.x;
    for (int i = t; i < nbuck; i += 256) hh[i] = 0;
    __syncthreads();
    int beg = c * CHUNK, end = min(beg + CHUNK, E);
    for (int k = beg + t; k < end; k += 256) atomicAdd(&hh[dst[k] >> BSH], 1);
    __syncthreads();
    for (int i = t; i < nbuck; i += 256) counts[i * nchunk + c] = hh[i];
}

__global__ void k_scan1(const int* __restrict__ in, int* __restrict__ bsum, int L)
{
    __shared__ int sd[256];
    int t = threadIdx.x;
    int i = blockIdx.x * 256 + t;
    sd[t] = (i < L) ? in[i] : 0;
    __syncthreads();
    for (int s = 128; s > 0; s >>= 1) {
        if (t < s) sd[t] += sd[t + s];
        __syncthreads();
    }
    if (t == 0) bsum[blockIdx.x] = sd[0];
}

__global__ void k_scan2(int* __restrict__ bsum, int nb)
{
    __shared__ int sd[512];
    int t = threadIdx.x;
    int v = (t < nb) ? bsum[t] : 0;
    sd[t] = v;
    __syncthreads();
    for (int o = 1; o < 512; o <<= 1) {
        int x = (t >= o) ? sd[t - o] : 0;
        __syncthreads();
        sd[t] += x;
        __syncthreads();
    }
    if (t < nb) bsum[t] = sd[t] - v;   // exclusive
}

__global__ void k_scan3(const int* __restrict__ in, const int* __restrict__ bsum,
                        int* __restrict__ out, int L)
{
    __shared__ int sd[256];
    int t = threadIdx.x;
    int i = blockIdx.x * 256 + t;
    int v = (i < L) ? in[i] : 0;
    sd[t] = v;
    __syncthreads();
    for (int o = 1; o < 256; o <<= 1) {
        int x = (t >= o) ? sd[t - o] : 0;
        __syncthreads();
        sd[t] += x;
        __syncthreads();
    }
    if (i < L) out[i] = bsum[blockIdx.x] + sd[t] - v;   // exclusive
}

__global__ void k_scatterb(const int* __restrict__ src, const int* __restrict__ dst,
                           const int* __restrict__ cstart, unsigned* __restrict__ tmp,
                           int E, int nchunk, int nbuck)
{
    __shared__ int cur[NBUCK_MAX];
    int c = blockIdx.x, t = threadIdx.x;
    for (int i = t; i < nbuck; i += 256) cur[i] = cstart[i * nchunk + c];
    __syncthreads();
    int beg = c * CHUNK, end = min(beg + CHUNK, E);
    for (int k = beg + t; k < end; k += 256) {
        int d = dst[k];
        int pos = atomicAdd(&cur[d >> BSH], 1);
        tmp[pos] = ((unsigned)(d & (BN - 1)) << 17) | (unsigned)src[k];
    }
}

__global__ void k_place2(const unsigned* __restrict__ tmp, const int* __restrict__ cstart,
                         int* __restrict__ csr, int* __restrict__ off_g, int* __restrict__ cnt_g,
                         int N, int E, int nchunk, int nbuck)
{
    __shared__ int lcnt[BN];
    __shared__ int lscan[256];
    __shared__ int lcur[BN];
    int b = blockIdx.x, t = threadIdx.x;
    int bstart = cstart[b * nchunk];
    int bend = (b + 1 < nbuck) ? cstart[(b + 1) * nchunk] : E;
    lcnt[t] = 0; lcnt[t + 256] = 0;
    __syncthreads();
    for (int k = bstart + t; k < bend; k += 256)
        atomicAdd(&lcnt[tmp[k] >> 17], 1);
    __syncthreads();
    int c0 = lcnt[2 * t], c1 = lcnt[2 * t + 1];
    int pair = c0 + c1;
    lscan[t] = pair;
    __syncthreads();
    for (int o = 1; o < 256; o <<= 1) {
        int x = (t >= o) ? lscan[t - o] : 0;
        __syncthreads();
        lscan[t] += x;
        __syncthreads();
    }
    int excl = lscan[t] - pair;
    int base = b << BSH;
    int n0 = base + 2 * t, n1 = n0 + 1;
    int o0 = bstart + excl, o1 = o0 + c0;
    lcur[2 * t] = o0; lcur[2 * t + 1] = o1;
    if (n0 < N) { off_g[n0] = o0; cnt_g[n0] = c0; }
    if (n1 < N) { off_g[n1] = o1; cnt_g[n1] = c1; }
    __syncthreads();
    for (int k = bstart + t; k < bend; k += 256) {
        unsigned v = tmp[k];
        int pos = atomicAdd(&lcur[v >> 17], 1);
        csr[pos] = (int)(v & 0x1FFFFu);
    }
}

// ---------- per-pass kernels ----------

template<bool RELU>
__global__ void k_node_proj(const float* __restrict__ x, const float* __restrict__ W,
                            const float* __restrict__ att_s, const float* __restrict__ att_d,
                            float* __restrict__ h, float* __restrict__ as_, float* __restrict__ ad_,
                            int N)
{
    __shared__ float Wl[Hd][Hd + 1];
    __shared__ float xr[8][Hd];
    int tid = threadIdx.x;
    for (int i = tid; i < Hd * Hd; i += 256) Wl[i >> 5][i & 31] = W[i];
    int li = tid >> 5, j = tid & 31;
    int node = blockIdx.x * 8 + li;
    float v = 0.f;
    if (node < N) v = x[(size_t)node * Hd + j];
    if (RELU) v = fmaxf(v, 0.f);
    xr[li][j] = v;
    __syncthreads();
    if (node >= N) return;
    float a = 0.f;
#pragma unroll
    for (int k = 0; k < Hd; k++) a += xr[li][k] * Wl[j][k];
    h[(size_t)node * Hd + j] = a;
    float s = a * att_s[j], d = a * att_d[j];
#pragma unroll
    for (int m = 16; m > 0; m >>= 1) { s += __shfl_xor(s, m, 32); d += __shfl_xor(d, m, 32); }
    if (j == 0) { as_[node] = s; ad_[node] = d; }
}

// One 32-lane group per dst node. Single-pass online softmax; float4 row loads:
// subgroup g=j>>3 handles edge t*4+g of each 32-edge chunk, quad q=j&7 covers
// columns 4q..4q+3. Tail lanes get score=-1e30 -> p=0 (loads cached self row).
__global__ void k_gather(const float* __restrict__ h, const float* __restrict__ as_,
                         const float* __restrict__ ad_, const int* __restrict__ cnt,
                         const int* __restrict__ off, const int* __restrict__ csr_src,
                         const float* __restrict__ bias, float* __restrict__ out, int N)
{
    int idx = blockIdx.x * 256 + threadIdx.x;
    int n = idx >> 5;
    if (n >= N) return;
    int j = idx & 31;
    int g = j >> 3, q = j & 7;
    int beg = off[n], deg = cnt[n];
    float adn = ad_[n];
    float self_sc = lrelu(as_[n] + adn);

    float m = self_sc;
    float denp = 0.f;
    float4 acc = make_float4(0.f, 0.f, 0.f, 0.f);

    for (int c = 0; c < deg; c += 32) {
        int k = c + j;
        int sj = n; float sc = -1e30f;
        if (k < deg) { sj = csr_src[beg + k]; sc = lrelu(as_[sj] + adn); }
        // chunk max -> update running max, rescale
        float cm = sc;
#pragma unroll
        for (int o = 16; o > 0; o >>= 1) cm = fmaxf(cm, __shfl_xor(cm, o, 32));
        float mn = fmaxf(m, cm);
        float scale = expf(m - mn);
        m = mn;
        acc.x *= scale; acc.y *= scale; acc.z *= scale; acc.w *= scale;
        denp *= scale;
        float pj = expf(sc - m);          // 0 for tail lanes
        denp += pj;
        // 8 iterations x 4 rows (one per subgroup), float4 per lane
#pragma unroll
        for (int t = 0; t < 8; t++) {
            int lsrc = t * 4 + g;
            float p = __shfl(pj, lsrc, 32);
            int   s = __shfl(sj, lsrc, 32);
            float4 rv = ((const float4*)(h + (size_t)s * Hd))[q];
            acc.x = fmaf(p, rv.x, acc.x);
            acc.y = fmaf(p, rv.y, acc.y);
            acc.z = fmaf(p, rv.z, acc.z);
            acc.w = fmaf(p, rv.w, acc.w);
        }
    }

    // self loop (added once: subgroup 0 only, then cross-subgroup reduce sums)
    float pself = expf(self_sc - m);
    if (g == 0) {
        float4 rv = ((const float4*)(h + (size_t)n * Hd))[q];
        acc.x = fmaf(pself, rv.x, acc.x);
        acc.y = fmaf(pself, rv.y, acc.y);
        acc.z = fmaf(pself, rv.z, acc.z);
        acc.w = fmaf(pself, rv.w, acc.w);
    }
#pragma unroll
    for (int o = 16; o > 0; o >>= 1) denp += __shfl_xor(denp, o, 32);
    float den = denp + pself;
#pragma unroll
    for (int o = 8; o <= 16; o <<= 1) {
        acc.x += __shfl_xor(acc.x, o, 32);
        acc.y += __shfl_xor(acc.y, o, 32);
        acc.z += __shfl_xor(acc.z, o, 32);
        acc.w += __shfl_xor(acc.w, o, 32);
    }
    if (g == 0) {
        float inv = 1.f / den;
        float4 b4 = ((const float4*)bias)[q];
        float4 o4;
        o4.x = fmaf(acc.x, inv, b4.x);
        o4.y = fmaf(acc.y, inv, b4.y);
        o4.z = fmaf(acc.z, inv, b4.z);
        o4.w = fmaf(acc.w, inv, b4.w);
        ((float4*)(out + (size_t)n * Hd))[q] = o4;
    }
}

__global__ void k_finish_gru(const float* __restrict__ gat,
                             const float* __restrict__ Wih0, const float* __restrict__ bih0,
                             const float* __restrict__ bhh0,
                             const float* __restrict__ Wih1, const float* __restrict__ bih1,
                             const float* __restrict__ bhh1,
                             float* __restrict__ out, int N)
{
    __shared__ float W0[3 * Hd][Hd + 1];
    __shared__ float W1[3 * Hd][Hd + 1];
    __shared__ float row[8][Hd];
    int tid = threadIdx.x;
    for (int i = tid; i < 3 * Hd * Hd; i += 256) {
        int r = i >> 5, c = i & 31;
        W0[r][c] = Wih0[i];
        W1[r][c] = Wih1[i];
    }
    int li = tid >> 5, j = tid & 31;
    int node = blockIdx.x * 8 + li;
    bool ok = node < N;
    float v = ok ? gat[(size_t)node * Hd + j] : 0.f;
    row[li][j] = v;
    __syncthreads();
    float gr = bih0[j], gz = bih0[Hd + j], gn = bih0[2 * Hd + j];
#pragma unroll
    for (int k = 0; k < Hd; k++) {
        float xv = row[li][k];
        gr += xv * W0[j][k];
        gz += xv * W0[Hd + j][k];
        gn += xv * W0[2 * Hd + j][k];
    }
    float r = 1.f / (1.f + expf(-(gr + bhh0[j])));
    float z = 1.f / (1.f + expf(-(gz + bhh0[Hd + j])));
    float nn = tanhf(gn + r * bhh0[2 * Hd + j]);
    float o = (1.f - z) * nn;
    __syncthreads();
    row[li][j] = o;
    __syncthreads();
    gr = bih1[j]; gz = bih1[Hd + j]; gn = bih1[2 * Hd + j];
#pragma unroll
    for (int k = 0; k < Hd; k++) {
        float xv = row[li][k];
        gr += xv * W1[j][k];
        gz += xv * W1[Hd + j][k];
        gn += xv * W1[2 * Hd + j][k];
    }
    r = 1.f / (1.f + expf(-(gr + bhh1[j])));
    z = 1.f / (1.f + expf(-(gz + bhh1[Hd + j])));
    nn = tanhf(gn + r * bhh1[2 * Hd + j]);
    if (ok) out[(size_t)node * Hd + j] = (1.f - z) * nn;
}

__global__ void k_finish_lin(const float* __restrict__ gat,
                             const float* __restrict__ linW, const float* __restrict__ linb,
                             float* __restrict__ out, int N)
{
    int idx = blockIdx.x * 256 + threadIdx.x;
    int node = idx >> 5;
    if (node >= N) return;
    int j = idx & 31;
    float sacc = gat[(size_t)node * Hd + j] * linW[j];
#pragma unroll
    for (int m = 16; m > 0; m >>= 1) sacc += __shfl_xor(sacc, m, 32);
    if (j == 0) out[node] = sacc + linb[0];
}

extern "C" void kernel_launch(void* const* d_in, const int* in_sizes, int n_in,
                              void* d_out, int out_size, void* d_ws, size_t ws_size,
                              hipStream_t stream)
{
    const float* x    = (const float*)d_in[0];
    const int*   ei   = (const int*)d_in[1];
    const float* W    = (const float*)d_in[2];
    const float* atts = (const float*)d_in[3];
    const float* attd = (const float*)d_in[4];
    const float* bias = (const float*)d_in[5];
    const float* Wih0 = (const float*)d_in[6];
    const float* bih0 = (const float*)d_in[8];
    const float* bhh0 = (const float*)d_in[9];
    const float* Wih1 = (const float*)d_in[10];
    const float* bih1 = (const float*)d_in[12];
    const float* bhh1 = (const float*)d_in[13];
    const float* linW = (const float*)d_in[14];
    const float* linb = (const float*)d_in[15];

    int N = in_sizes[0] / Hd;
    int E = in_sizes[1] / 2;
    const int* src = ei;
    const int* dst = ei + E;
    int nbuck = (N + BN - 1) >> BSH;          // 196 for N=100000
    int nchunk = (E + CHUNK - 1) / CHUNK;     // 293 for E=2.4M
    int L = nbuck * nchunk;                   // 57428
    int nbL = (L + 255) / 256;                // 225 (<=512)

    // workspace carve (every slot rewritten before any read, each launch)
    float* h     = (float*)d_ws;                 // [N,32]
    float* gat   = h   + (size_t)N * Hd;         // [N,32]  (tmp aliases this)
    float* h2    = gat + (size_t)N * Hd;         // [N,32]
    float* as_   = h2  + (size_t)N * Hd;         // [N]
    float* ad_   = as_ + N;                      // [N]
    int*   cnt   = (int*)(ad_ + N);              // [N]
    int*   off   = cnt + N;                      // [N]
    int*   counts= off + N;                      // [L]
    int*   cstart= counts + L;                   // [L]
    int*   bsum  = cstart + L;                   // [512]
    int*   csr   = bsum + 512;                   // [E]
    unsigned* tmp = (unsigned*)gat;              // [E] aliases gat (disjoint lifetime)

    dim3 blk(256);
    dim3 g_node8((N + 7) / 8);
    dim3 g_nf((N * Hd + 255) / 256);

    // ---- CSR build (once; shared by both GAT passes) ----
    hipLaunchKernelGGL(k_histb, dim3(nchunk), blk, 0, stream, dst, counts, E, nchunk, nbuck);
    hipLaunchKernelGGL(k_scan1, dim3(nbL), blk, 0, stream, counts, bsum, L);
    hipLaunchKernelGGL(k_scan2, dim3(1), dim3(512), 0, stream, bsum, nbL);
    hipLaunchKernelGGL(k_scan3, dim3(nbL), blk, 0, stream, counts, bsum, cstart, L);
    hipLaunchKernelGGL(k_scatterb, dim3(nchunk), blk, 0, stream, src, dst, cstart, tmp, E, nchunk, nbuck);
    hipLaunchKernelGGL(k_place2, dim3(nbuck), blk, 0, stream, tmp, cstart, csr, off, cnt, N, E, nchunk, nbuck);

    // ---- GAT pass 1 (input = relu(x)) + GRU0 + GRU1 ----
    hipLaunchKernelGGL((k_node_proj<true>), g_node8, blk, 0, stream, x, W, atts, attd, h, as_, ad_, N);
    hipLaunchKernelGGL(k_gather, g_nf, blk, 0, stream, h, as_, ad_, cnt, off, csr, bias, gat, N);
    hipLaunchKernelGGL(k_finish_gru, g_node8, blk, 0, stream, gat,
                       Wih0, bih0, bhh0, Wih1, bih1, bhh1, h2, N);

    // ---- GAT pass 2 (input = h2) + linear ----
    hipLaunchKernelGGL((k_node_proj<false>), g_node8, blk, 0, stream, h2, W, atts, attd, h, as_, ad_, N);
    hipLaunchKernelGGL(k_gather, g_nf, blk, 0, stream, h, as_, ad_, cnt, off, csr, bias, gat, N);
    hipLaunchKernelGGL(k_finish_lin, g_nf, blk, 0, stream, gat, linW, linb, (float*)d_out, N);
}

// Round 8
// 258.105 us; speedup vs baseline: 4.2280x; 1.0558x over previous
//
#include <hip/hip_runtime.h>
#include <math.h>

#define Hd 32
#define NEG 0.2f
#define BSH 9                  // 512 nodes per bucket
#define BN (1 << BSH)
#define CHUNK 8192
#define NBUCK_MAX 256
#define WP 36                  // padded W row stride (floats): 144 B, 16B-aligned, bank-optimal

__device__ __forceinline__ float lrelu(float x) { return x > 0.f ? x : NEG * x; }
__device__ __forceinline__ float fsigm(float x) { return 1.f / (1.f + __expf(-x)); }
__device__ __forceinline__ float ftanh(float x) { return 1.f - 2.f / (__expf(2.f * x) + 1.f); }

// ---------- CSR build: chunk x bucket counting sort (no global atomics) ----------

__global__ void k_histb(const int* __restrict__ dst, int* __restrict__ counts,
                        int E, int nchunk, int nbuck)
{
    __shared__ int hh[NBUCK_MAX];
    int c = blockIdx.x, t = threadIdx.x;
    for (int i = t; i < nbuck; i += 256) hh[i] = 0;
    __syncthreads();
    int beg = c * CHUNK, end = min(beg + CHUNK, E);
    for (int k = beg + t; k < end; k += 256) atomicAdd(&hh[dst[k] >> BSH], 1);
    __syncthreads();
    for (int i = t; i < nbuck; i += 256) counts[i * nchunk + c] = hh[i];
}

__global__ void k_scan1(const int* __restrict__ in, int* __restrict__ bsum, int L)
{
    __shared__ int sd[256];
    int t = threadIdx.x;
    int i = blockIdx.x * 256 + t;
    sd[t] = (i < L) ? in[i] : 0;
    __syncthreads();
    for (int s = 128; s > 0; s >>= 1) {
        if (t < s) sd[t] += sd[t + s];
        __syncthreads();
    }
    if (t == 0) bsum[blockIdx.x] = sd[0];
}

__global__ void k_scan2(int* __restrict__ bsum, int nb)
{
    __shared__ int sd[512];
    int t = threadIdx.x;
    int v = (t < nb) ? bsum[t] : 0;
    sd[t] = v;
    __syncthreads();
    for (int o = 1; o < 512; o <<= 1) {
        int x = (t >= o) ? sd[t - o] : 0;
        __syncthreads();
        sd[t] += x;
        __syncthreads();
    }
    if (t < nb) bsum[t] = sd[t] - v;   // exclusive
}

__global__ void k_scan3(const int* __restrict__ in, const int* __restrict__ bsum,
                        int* __restrict__ out, int L)
{
    __shared__ int sd[256];
    int t = threadIdx.x;
    int i = blockIdx.x * 256 + t;
    int v = (i < L) ? in[i] : 0;
    sd[t] = v;
    __syncthreads();
    for (int o = 1; o < 256; o <<= 1) {
        int x = (t >= o) ? sd[t - o] : 0;
        __syncthreads();
        sd[t] += x;
        __syncthreads();
    }
    if (i < L) out[i] = bsum[blockIdx.x] + sd[t] - v;   // exclusive
}

__global__ void k_scatterb(const int* __restrict__ src, const int* __restrict__ dst,
                           const int* __restrict__ cstart, unsigned* __restrict__ tmp,
                           int E, int nchunk, int nbuck)
{
    __shared__ int cur[NBUCK_MAX];
    int c = blockIdx.x, t = threadIdx.x;
    for (int i = t; i < nbuck; i += 256) cur[i] = cstart[i * nchunk + c];
    __syncthreads();
    int beg = c * CHUNK, end = min(beg + CHUNK, E);
    for (int k = beg + t; k < end; k += 256) {
        int d = dst[k];
        int pos = atomicAdd(&cur[d >> BSH], 1);
        tmp[pos] = ((unsigned)(d & (BN - 1)) << 17) | (unsigned)src[k];
    }
}

__global__ void k_place2(const unsigned* __restrict__ tmp, const int* __restrict__ cstart,
                         int* __restrict__ csr, int* __restrict__ off_g, int* __restrict__ cnt_g,
                         int N, int E, int nchunk, int nbuck)
{
    __shared__ int lcnt[BN];
    __shared__ int lscan[256];
    __shared__ int lcur[BN];
    int b = blockIdx.x, t = threadIdx.x;
    int bstart = cstart[b * nchunk];
    int bend = (b + 1 < nbuck) ? cstart[(b + 1) * nchunk] : E;
    lcnt[t] = 0; lcnt[t + 256] = 0;
    __syncthreads();
    for (int k = bstart + t; k < bend; k += 256)
        atomicAdd(&lcnt[tmp[k] >> 17], 1);
    __syncthreads();
    int c0 = lcnt[2 * t], c1 = lcnt[2 * t + 1];
    int pair = c0 + c1;
    lscan[t] = pair;
    __syncthreads();
    for (int o = 1; o < 256; o <<= 1) {
        int x = (t >= o) ? lscan[t - o] : 0;
        __syncthreads();
        lscan[t] += x;
        __syncthreads();
    }
    int excl = lscan[t] - pair;
    int base = b << BSH;
    int n0 = base + 2 * t, n1 = n0 + 1;
    int o0 = bstart + excl, o1 = o0 + c0;
    lcur[2 * t] = o0; lcur[2 * t + 1] = o1;
    if (n0 < N) { off_g[n0] = o0; cnt_g[n0] = c0; }
    if (n1 < N) { off_g[n1] = o1; cnt_g[n1] = c1; }
    __syncthreads();
    for (int k = bstart + t; k < bend; k += 256) {
        unsigned v = tmp[k];
        int pos = atomicAdd(&lcur[v >> 17], 1);
        csr[pos] = (int)(v & 0x1FFFFu);
    }
}

// ---------- per-pass kernels ----------

template<bool RELU>
__global__ void k_node_proj(const float* __restrict__ x, const float* __restrict__ W,
                            const float* __restrict__ att_s, const float* __restrict__ att_d,
                            float* __restrict__ h, float* __restrict__ as_, float* __restrict__ ad_,
                            int N)
{
    __shared__ float Wl[Hd][Hd + 1];
    __shared__ float xr[8][Hd];
    int tid = threadIdx.x;
    for (int i = tid; i < Hd * Hd; i += 256) Wl[i >> 5][i & 31] = W[i];
    int li = tid >> 5, j = tid & 31;
    int node = blockIdx.x * 8 + li;
    float v = 0.f;
    if (node < N) v = x[(size_t)node * Hd + j];
    if (RELU) v = fmaxf(v, 0.f);
    xr[li][j] = v;
    __syncthreads();
    if (node >= N) return;
    float a = 0.f;
#pragma unroll
    for (int k = 0; k < Hd; k++) a += xr[li][k] * Wl[j][k];
    h[(size_t)node * Hd + j] = a;
    float s = a * att_s[j], d = a * att_d[j];
#pragma unroll
    for (int m = 16; m > 0; m >>= 1) { s += __shfl_xor(s, m, 32); d += __shfl_xor(d, m, 32); }
    if (j == 0) { as_[node] = s; ad_[node] = d; }
}

// One 32-lane group per dst node. Single-pass online softmax; float4 row loads.
__global__ void k_gather(const float* __restrict__ h, const float* __restrict__ as_,
                         const float* __restrict__ ad_, const int* __restrict__ cnt,
                         const int* __restrict__ off, const int* __restrict__ csr_src,
                         const float* __restrict__ bias, float* __restrict__ out, int N)
{
    int idx = blockIdx.x * 256 + threadIdx.x;
    int n = idx >> 5;
    if (n >= N) return;
    int j = idx & 31;
    int g = j >> 3, q = j & 7;
    int beg = off[n], deg = cnt[n];
    float adn = ad_[n];
    float self_sc = lrelu(as_[n] + adn);

    float m = self_sc;
    float denp = 0.f;
    float4 acc = make_float4(0.f, 0.f, 0.f, 0.f);

    for (int c = 0; c < deg; c += 32) {
        int k = c + j;
        int sj = n; float sc = -1e30f;
        if (k < deg) { sj = csr_src[beg + k]; sc = lrelu(as_[sj] + adn); }
        float cm = sc;
#pragma unroll
        for (int o = 16; o > 0; o >>= 1) cm = fmaxf(cm, __shfl_xor(cm, o, 32));
        float mn = fmaxf(m, cm);
        float scale = __expf(m - mn);
        m = mn;
        acc.x *= scale; acc.y *= scale; acc.z *= scale; acc.w *= scale;
        denp *= scale;
        float pj = __expf(sc - m);        // 0 for tail lanes
        denp += pj;
#pragma unroll
        for (int t = 0; t < 8; t++) {
            int lsrc = t * 4 + g;
            float p = __shfl(pj, lsrc, 32);
            int   s = __shfl(sj, lsrc, 32);
            float4 rv = ((const float4*)(h + (size_t)s * Hd))[q];
            acc.x = fmaf(p, rv.x, acc.x);
            acc.y = fmaf(p, rv.y, acc.y);
            acc.z = fmaf(p, rv.z, acc.z);
            acc.w = fmaf(p, rv.w, acc.w);
        }
    }

    float pself = __expf(self_sc - m);
    if (g == 0) {
        float4 rv = ((const float4*)(h + (size_t)n * Hd))[q];
        acc.x = fmaf(pself, rv.x, acc.x);
        acc.y = fmaf(pself, rv.y, acc.y);
        acc.z = fmaf(pself, rv.z, acc.z);
        acc.w = fmaf(pself, rv.w, acc.w);
    }
#pragma unroll
    for (int o = 16; o > 0; o >>= 1) denp += __shfl_xor(denp, o, 32);
    float den = denp + pself;
#pragma unroll
    for (int o = 8; o <= 16; o <<= 1) {
        acc.x += __shfl_xor(acc.x, o, 32);
        acc.y += __shfl_xor(acc.y, o, 32);
        acc.z += __shfl_xor(acc.z, o, 32);
        acc.w += __shfl_xor(acc.w, o, 32);
    }
    if (g == 0) {
        float inv = 1.f / den;
        float4 b4 = ((const float4*)bias)[q];
        float4 o4;
        o4.x = fmaf(acc.x, inv, b4.x);
        o4.y = fmaf(acc.y, inv, b4.y);
        o4.z = fmaf(acc.z, inv, b4.z);
        o4.w = fmaf(acc.w, inv, b4.w);
        ((float4*)(out + (size_t)n * Hd))[q] = o4;
    }
}

// GRU0+GRU1, h_prev=0. 32-lane group handles 4 nodes; W in LDS (stride WP=36,
// ds_read_b128 bank-optimal); rows read as uniform float4 (broadcast). Fast exp.
__global__ __launch_bounds__(256) void k_finish_gru(
    const float* __restrict__ gat,
    const float* __restrict__ Wih0, const float* __restrict__ bih0, const float* __restrict__ bhh0,
    const float* __restrict__ Wih1, const float* __restrict__ bih1, const float* __restrict__ bhh1,
    float* __restrict__ out, int N)
{
    __shared__ __align__(16) float W0[96 * WP];
    __shared__ __align__(16) float W1[96 * WP];
    __shared__ __align__(16) float rows[8][4][Hd];
    int tid = threadIdx.x;
    for (int i = tid; i < 96 * Hd; i += 256) {
        int r = i >> 5, k = i & 31;
        W0[r * WP + k] = Wih0[i];
        W1[r * WP + k] = Wih1[i];
    }
    int g = tid >> 5, j = tid & 31;
    int node0 = blockIdx.x * 32 + g * 4;
#pragma unroll
    for (int i = 0; i < 4; i++) {
        int node = node0 + i;
        rows[g][i][j] = (node < N) ? gat[(size_t)node * Hd + j] : 0.f;
    }
    float br0 = bih0[j], bz0 = bih0[32 + j], bn0 = bih0[64 + j];
    float hr0 = bhh0[j], hz0 = bhh0[32 + j], hn0 = bhh0[64 + j];
    float br1 = bih1[j], bz1 = bih1[32 + j], bn1 = bih1[64 + j];
    float hr1 = bhh1[j], hz1 = bhh1[32 + j], hn1 = bhh1[64 + j];
    __syncthreads();

    float o1v[4];
    {
        float ar[4], az[4], an[4];
#pragma unroll
        for (int i = 0; i < 4; i++) { ar[i] = br0; az[i] = bz0; an[i] = bn0; }
#pragma unroll
        for (int k4 = 0; k4 < 8; k4++) {
            float4 wr = *(const float4*)&W0[(j     ) * WP + k4 * 4];
            float4 wz = *(const float4*)&W0[(32 + j) * WP + k4 * 4];
            float4 wn = *(const float4*)&W0[(64 + j) * WP + k4 * 4];
#pragma unroll
            for (int i = 0; i < 4; i++) {
                float4 xv = *(const float4*)&rows[g][i][k4 * 4];
                ar[i] = fmaf(xv.x, wr.x, ar[i]); ar[i] = fmaf(xv.y, wr.y, ar[i]);
                ar[i] = fmaf(xv.z, wr.z, ar[i]); ar[i] = fmaf(xv.w, wr.w, ar[i]);
                az[i] = fmaf(xv.x, wz.x, az[i]); az[i] = fmaf(xv.y, wz.y, az[i]);
                az[i] = fmaf(xv.z, wz.z, az[i]); az[i] = fmaf(xv.w, wz.w, az[i]);
                an[i] = fmaf(xv.x, wn.x, an[i]); an[i] = fmaf(xv.y, wn.y, an[i]);
                an[i] = fmaf(xv.z, wn.z, an[i]); an[i] = fmaf(xv.w, wn.w, an[i]);
            }
        }
#pragma unroll
        for (int i = 0; i < 4; i++) {
            float r = fsigm(ar[i] + hr0);
            float z = fsigm(az[i] + hz0);
            float t = ftanh(an[i] + r * hn0);
            o1v[i] = (1.f - z) * t;
        }
    }
    __syncthreads();
#pragma unroll
    for (int i = 0; i < 4; i++) rows[g][i][j] = o1v[i];
    __syncthreads();
    float o2v[4];
    {
        float ar[4], az[4], an[4];
#pragma unroll
        for (int i = 0; i < 4; i++) { ar[i] = br1; az[i] = bz1; an[i] = bn1; }
#pragma unroll
        for (int k4 = 0; k4 < 8; k4++) {
            float4 wr = *(const float4*)&W1[(j     ) * WP + k4 * 4];
            float4 wz = *(const float4*)&W1[(32 + j) * WP + k4 * 4];
            float4 wn = *(const float4*)&W1[(64 + j) * WP + k4 * 4];
#pragma unroll
            for (int i = 0; i < 4; i++) {
                float4 xv = *(const float4*)&rows[g][i][k4 * 4];
                ar[i] = fmaf(xv.x, wr.x, ar[i]); ar[i] = fmaf(xv.y, wr.y, ar[i]);
                ar[i] = fmaf(xv.z, wr.z, ar[i]); ar[i] = fmaf(xv.w, wr.w, ar[i]);
                az[i] = fmaf(xv.x, wz.x, az[i]); az[i] = fmaf(xv.y, wz.y, az[i]);
                az[i] = fmaf(xv.z, wz.z, az[i]); az[i] = fmaf(xv.w, wz.w, az[i]);
                an[i] = fmaf(xv.x, wn.x, an[i]); an[i] = fmaf(xv.y, wn.y, an[i]);
                an[i] = fmaf(xv.z, wn.z, an[i]); an[i] = fmaf(xv.w, wn.w, an[i]);
            }
        }
#pragma unroll
        for (int i = 0; i < 4; i++) {
            float r = fsigm(ar[i] + hr1);
            float z = fsigm(az[i] + hz1);
            float t = ftanh(an[i] + r * hn1);
            o2v[i] = (1.f - z) * t;
        }
    }
#pragma unroll
    for (int i = 0; i < 4; i++) {
        int node = node0 + i;
        if (node < N) out[(size_t)node * Hd + j] = o2v[i];
    }
}

__global__ void k_finish_lin(const float* __restrict__ gat,
                             const float* __restrict__ linW, const float* __restrict__ linb,
                             float* __restrict__ out, int N)
{
    int idx = blockIdx.x * 256 + threadIdx.x;
    int node = idx >> 5;
    if (node >= N) return;
    int j = idx & 31;
    float sacc = gat[(size_t)node * Hd + j] * linW[j];
#pragma unroll
    for (int m = 16; m > 0; m >>= 1) sacc += __shfl_xor(sacc, m, 32);
    if (j == 0) out[node] = sacc + linb[0];
}

extern "C" void kernel_launch(void* const* d_in, const int* in_sizes, int n_in,
                              void* d_out, int out_size, void* d_ws, size_t ws_size,
                              hipStream_t stream)
{
    const float* x    = (const float*)d_in[0];
    const int*   ei   = (const int*)d_in[1];
    const float* W    = (const float*)d_in[2];
    const float* atts = (const float*)d_in[3];
    const float* attd = (const float*)d_in[4];
    const float* bias = (const float*)d_in[5];
    const float* Wih0 = (const float*)d_in[6];
    const float* bih0 = (const float*)d_in[8];
    const float* bhh0 = (const float*)d_in[9];
    const float* Wih1 = (const float*)d_in[10];
    const float* bih1 = (const float*)d_in[12];
    const float* bhh1 = (const float*)d_in[13];
    const float* linW = (const float*)d_in[14];
    const float* linb = (const float*)d_in[15];

    int N = in_sizes[0] / Hd;
    int E = in_sizes[1] / 2;
    const int* src = ei;
    const int* dst = ei + E;
    int nbuck = (N + BN - 1) >> BSH;          // 196 for N=100000
    int nchunk = (E + CHUNK - 1) / CHUNK;     // 293 for E=2.4M
    int L = nbuck * nchunk;                   // 57428
    int nbL = (L + 255) / 256;                // 225 (<=512)

    // workspace carve (every slot rewritten before any read, each launch)
    float* h     = (float*)d_ws;                 // [N,32]
    float* gat   = h   + (size_t)N * Hd;         // [N,32]  (tmp aliases this)
    float* h2    = gat + (size_t)N * Hd;         // [N,32]
    float* as_   = h2  + (size_t)N * Hd;         // [N]
    float* ad_   = as_ + N;                      // [N]
    int*   cnt   = (int*)(ad_ + N);              // [N]
    int*   off   = cnt + N;                      // [N]
    int*   counts= off + N;                      // [L]
    int*   cstart= counts + L;                   // [L]
    int*   bsum  = cstart + L;                   // [512]
    int*   csr   = bsum + 512;                   // [E]
    unsigned* tmp = (unsigned*)gat;              // [E] aliases gat (disjoint lifetime)

    dim3 blk(256);
    dim3 g_node8((N + 7) / 8);
    dim3 g_nf((N * Hd + 255) / 256);
    dim3 g_gru((N + 31) / 32);

    // ---- CSR build (once; shared by both GAT passes) ----
    hipLaunchKernelGGL(k_histb, dim3(nchunk), blk, 0, stream, dst, counts, E, nchunk, nbuck);
    hipLaunchKernelGGL(k_scan1, dim3(nbL), blk, 0, stream, counts, bsum, L);
    hipLaunchKernelGGL(k_scan2, dim3(1), dim3(512), 0, stream, bsum, nbL);
    hipLaunchKernelGGL(k_scan3, dim3(nbL), blk, 0, stream, counts, bsum, cstart, L);
    hipLaunchKernelGGL(k_scatterb, dim3(nchunk), blk, 0, stream, src, dst, cstart, tmp, E, nchunk, nbuck);
    hipLaunchKernelGGL(k_place2, dim3(nbuck), blk, 0, stream, tmp, cstart, csr, off, cnt, N, E, nchunk, nbuck);

    // ---- GAT pass 1 (input = relu(x)) + GRU0 + GRU1 ----
    hipLaunchKernelGGL((k_node_proj<true>), g_node8, blk, 0, stream, x, W, atts, attd, h, as_, ad_, N);
    hipLaunchKernelGGL(k_gather, g_nf, blk, 0, stream, h, as_, ad_, cnt, off, csr, bias, gat, N);
    hipLaunchKernelGGL(k_finish_gru, g_gru, blk, 0, stream, gat,
                       Wih0, bih0, bhh0, Wih1, bih1, bhh1, h2, N);

    // ---- GAT pass 2 (input = h2) + linear ----
    hipLaunchKernelGGL((k_node_proj<false>), g_node8, blk, 0, stream, h2, W, atts, attd, h, as_, ad_, N);
    hipLaunchKernelGGL(k_gather, g_nf, blk, 0, stream, h, as_, ad_, cnt, off, csr, bias, gat, N);
    hipLaunchKernelGGL(k_finish_lin, g_nf, blk, 0, stream, gat, linW, linb, (float*)d_out, N);
}

// Round 9
// 250.868 us; speedup vs baseline: 4.3500x; 1.0288x over previous
//
#include <hip/hip_runtime.h>
#include <math.h>

#define Hd 32
#define NEG 0.2f
#define BSH 9                  // 512 nodes per bucket
#define BN (1 << BSH)
#define CHUNK 8192
#define NBUCK_MAX 256
#define WP 36                  // padded W row stride (floats): 144 B, 16B-aligned, bank-optimal

__device__ __forceinline__ float lrelu(float x) { return x > 0.f ? x : NEG * x; }
__device__ __forceinline__ float fsigm(float x) { return 1.f / (1.f + __expf(-x)); }
__device__ __forceinline__ float ftanh(float x) { return 1.f - 2.f / (__expf(2.f * x) + 1.f); }

// ---------- CSR build: chunk x bucket counting sort (no global atomics) ----------

__global__ void k_histb(const int* __restrict__ dst, int* __restrict__ counts,
                        int E, int nchunk, int nbuck)
{
    __shared__ int hh[NBUCK_MAX];
    int c = blockIdx.x, t = threadIdx.x;
    for (int i = t; i < nbuck; i += 256) hh[i] = 0;
    __syncthreads();
    int beg = c * CHUNK, end = min(beg + CHUNK, E);
    for (int k = beg + t; k < end; k += 256) atomicAdd(&hh[dst[k] >> BSH], 1);
    __syncthreads();
    for (int i = t; i < nbuck; i += 256) counts[i * nchunk + c] = hh[i];
}

__global__ void k_scan1(const int* __restrict__ in, int* __restrict__ bsum, int L)
{
    __shared__ int sd[256];
    int t = threadIdx.x;
    int i = blockIdx.x * 256 + t;
    sd[t] = (i < L) ? in[i] : 0;
    __syncthreads();
    for (int s = 128; s > 0; s >>= 1) {
        if (t < s) sd[t] += sd[t + s];
        __syncthreads();
    }
    if (t == 0) bsum[blockIdx.x] = sd[0];
}

__global__ void k_scan2(int* __restrict__ bsum, int nb)
{
    __shared__ int sd[512];
    int t = threadIdx.x;
    int v = (t < nb) ? bsum[t] : 0;
    sd[t] = v;
    __syncthreads();
    for (int o = 1; o < 512; o <<= 1) {
        int x = (t >= o) ? sd[t - o] : 0;
        __syncthreads();
        sd[t] += x;
        __syncthreads();
    }
    if (t < nb) bsum[t] = sd[t] - v;   // exclusive
}

__global__ void k_scan3(const int* __restrict__ in, const int* __restrict__ bsum,
                        int* __restrict__ out, int L)
{
    __shared__ int sd[256];
    int t = threadIdx.x;
    int i = blockIdx.x * 256 + t;
    int v = (i < L) ? in[i] : 0;
    sd[t] = v;
    __syncthreads();
    for (int o = 1; o < 256; o <<= 1) {
        int x = (t >= o) ? sd[t - o] : 0;
        __syncthreads();
        sd[t] += x;
        __syncthreads();
    }
    if (i < L) out[i] = bsum[blockIdx.x] + sd[t] - v;   // exclusive
}

__global__ void k_scatterb(const int* __restrict__ src, const int* __restrict__ dst,
                           const int* __restrict__ cstart, unsigned* __restrict__ tmp,
                           int E, int nchunk, int nbuck)
{
    __shared__ int cur[NBUCK_MAX];
    int c = blockIdx.x, t = threadIdx.x;
    for (int i = t; i < nbuck; i += 256) cur[i] = cstart[i * nchunk + c];
    __syncthreads();
    int beg = c * CHUNK, end = min(beg + CHUNK, E);
    for (int k = beg + t; k < end; k += 256) {
        int d = dst[k];
        int pos = atomicAdd(&cur[d >> BSH], 1);
        tmp[pos] = ((unsigned)(d & (BN - 1)) << 17) | (unsigned)src[k];
    }
}

__global__ void k_place2(const unsigned* __restrict__ tmp, const int* __restrict__ cstart,
                         int* __restrict__ csr, int* __restrict__ off_g, int* __restrict__ cnt_g,
                         int N, int E, int nchunk, int nbuck)
{
    __shared__ int lcnt[BN];
    __shared__ int lscan[256];
    __shared__ int lcur[BN];
    int b = blockIdx.x, t = threadIdx.x;
    int bstart = cstart[b * nchunk];
    int bend = (b + 1 < nbuck) ? cstart[(b + 1) * nchunk] : E;
    lcnt[t] = 0; lcnt[t + 256] = 0;
    __syncthreads();
    for (int k = bstart + t; k < bend; k += 256)
        atomicAdd(&lcnt[tmp[k] >> 17], 1);
    __syncthreads();
    int c0 = lcnt[2 * t], c1 = lcnt[2 * t + 1];
    int pair = c0 + c1;
    lscan[t] = pair;
    __syncthreads();
    for (int o = 1; o < 256; o <<= 1) {
        int x = (t >= o) ? lscan[t - o] : 0;
        __syncthreads();
        lscan[t] += x;
        __syncthreads();
    }
    int excl = lscan[t] - pair;
    int base = b << BSH;
    int n0 = base + 2 * t, n1 = n0 + 1;
    int o0 = bstart + excl, o1 = o0 + c0;
    lcur[2 * t] = o0; lcur[2 * t + 1] = o1;
    if (n0 < N) { off_g[n0] = o0; cnt_g[n0] = c0; }
    if (n1 < N) { off_g[n1] = o1; cnt_g[n1] = c1; }
    __syncthreads();
    for (int k = bstart + t; k < bend; k += 256) {
        unsigned v = tmp[k];
        int pos = atomicAdd(&lcur[v >> 17], 1);
        csr[pos] = (int)(v & 0x1FFFFu);
    }
}

// ---------- per-pass kernels ----------

template<bool RELU>
__global__ void k_node_proj(const float* __restrict__ x, const float* __restrict__ W,
                            const float* __restrict__ att_s, const float* __restrict__ att_d,
                            float* __restrict__ h, float* __restrict__ as_, float* __restrict__ ad_,
                            int N)
{
    __shared__ float Wl[Hd][Hd + 1];
    __shared__ float xr[8][Hd];
    int tid = threadIdx.x;
    for (int i = tid; i < Hd * Hd; i += 256) Wl[i >> 5][i & 31] = W[i];
    int li = tid >> 5, j = tid & 31;
    int node = blockIdx.x * 8 + li;
    float v = 0.f;
    if (node < N) v = x[(size_t)node * Hd + j];
    if (RELU) v = fmaxf(v, 0.f);
    xr[li][j] = v;
    __syncthreads();
    if (node >= N) return;
    float a = 0.f;
#pragma unroll
    for (int k = 0; k < Hd; k++) a += xr[li][k] * Wl[j][k];
    h[(size_t)node * Hd + j] = a;
    float s = a * att_s[j], d = a * att_d[j];
#pragma unroll
    for (int m = 16; m > 0; m >>= 1) { s += __shfl_xor(s, m, 32); d += __shfl_xor(d, m, 32); }
    if (j == 0) { as_[node] = s; ad_[node] = d; }
}

// One 32-lane group per dst node. Single-pass online softmax; float4 row loads.
// MODE 0: out row = acc/den + bias (float4 store by subgroup 0)
// MODE 1: out[n] = dot(acc/den + bias, linW) + linb  (fused final linear)
template<int MODE>
__global__ void k_gather(const float* __restrict__ h, const float* __restrict__ as_,
                         const float* __restrict__ ad_, const int* __restrict__ cnt,
                         const int* __restrict__ off, const int* __restrict__ csr_src,
                         const float* __restrict__ bias, const float* __restrict__ linW,
                         const float* __restrict__ linb, float* __restrict__ out, int N)
{
    int idx = blockIdx.x * 256 + threadIdx.x;
    int n = idx >> 5;
    if (n >= N) return;
    int j = idx & 31;
    int g = j >> 3, q = j & 7;
    int beg = off[n], deg = cnt[n];
    float adn = ad_[n];
    float self_sc = lrelu(as_[n] + adn);

    float m = self_sc;
    float denp = 0.f;
    float4 acc = make_float4(0.f, 0.f, 0.f, 0.f);

    for (int c = 0; c < deg; c += 32) {
        int k = c + j;
        int sj = n; float sc = -1e30f;
        if (k < deg) { sj = csr_src[beg + k]; sc = lrelu(as_[sj] + adn); }
        float cm = sc;
#pragma unroll
        for (int o = 16; o > 0; o >>= 1) cm = fmaxf(cm, __shfl_xor(cm, o, 32));
        float mn = fmaxf(m, cm);
        float scale = __expf(m - mn);
        m = mn;
        acc.x *= scale; acc.y *= scale; acc.z *= scale; acc.w *= scale;
        denp *= scale;
        float pj = __expf(sc - m);        // 0 for tail lanes
        denp += pj;
#pragma unroll
        for (int t = 0; t < 8; t++) {
            int lsrc = t * 4 + g;
            float p = __shfl(pj, lsrc, 32);
            int   s = __shfl(sj, lsrc, 32);
            float4 rv = ((const float4*)(h + (size_t)s * Hd))[q];
            acc.x = fmaf(p, rv.x, acc.x);
            acc.y = fmaf(p, rv.y, acc.y);
            acc.z = fmaf(p, rv.z, acc.z);
            acc.w = fmaf(p, rv.w, acc.w);
        }
    }

    float pself = __expf(self_sc - m);
    if (g == 0) {
        float4 rv = ((const float4*)(h + (size_t)n * Hd))[q];
        acc.x = fmaf(pself, rv.x, acc.x);
        acc.y = fmaf(pself, rv.y, acc.y);
        acc.z = fmaf(pself, rv.z, acc.z);
        acc.w = fmaf(pself, rv.w, acc.w);
    }
#pragma unroll
    for (int o = 16; o > 0; o >>= 1) denp += __shfl_xor(denp, o, 32);
    float den = denp + pself;
#pragma unroll
    for (int o = 8; o <= 16; o <<= 1) {
        acc.x += __shfl_xor(acc.x, o, 32);
        acc.y += __shfl_xor(acc.y, o, 32);
        acc.z += __shfl_xor(acc.z, o, 32);
        acc.w += __shfl_xor(acc.w, o, 32);
    }
    float inv = 1.f / den;
    float4 b4 = ((const float4*)bias)[q];
    if (MODE == 0) {
        if (g == 0) {
            float4 o4;
            o4.x = fmaf(acc.x, inv, b4.x);
            o4.y = fmaf(acc.y, inv, b4.y);
            o4.z = fmaf(acc.z, inv, b4.z);
            o4.w = fmaf(acc.w, inv, b4.w);
            ((float4*)(out + (size_t)n * Hd))[q] = o4;
        }
    } else {
        float4 w4 = ((const float4*)linW)[q];
        float s = fmaf(acc.x, inv, b4.x) * w4.x
                + fmaf(acc.y, inv, b4.y) * w4.y
                + fmaf(acc.z, inv, b4.z) * w4.z
                + fmaf(acc.w, inv, b4.w) * w4.w;
#pragma unroll
        for (int o = 1; o <= 4; o <<= 1) s += __shfl_xor(s, o, 32);
        if (j == 0) out[n] = s + linb[0];
    }
}

// GRU0+GRU1, h_prev=0. 32-lane group handles 4 nodes; 4 tiles per block (128 nodes)
// amortize the W LDS staging. W stride WP=36 (ds_read_b128 bank-optimal); rows read
// as uniform float4 (broadcast). Fast exp.
__global__ __launch_bounds__(256) void k_finish_gru(
    const float* __restrict__ gat,
    const float* __restrict__ Wih0, const float* __restrict__ bih0, const float* __restrict__ bhh0,
    const float* __restrict__ Wih1, const float* __restrict__ bih1, const float* __restrict__ bhh1,
    float* __restrict__ out, int N)
{
    __shared__ __align__(16) float W0[96 * WP];
    __shared__ __align__(16) float W1[96 * WP];
    __shared__ __align__(16) float rows[8][4][Hd];
    int tid = threadIdx.x;
    for (int i = tid; i < 96 * Hd; i += 256) {
        int r = i >> 5, k = i & 31;
        W0[r * WP + k] = Wih0[i];
        W1[r * WP + k] = Wih1[i];
    }
    int g = tid >> 5, j = tid & 31;
    float br0 = bih0[j], bz0 = bih0[32 + j], bn0 = bih0[64 + j];
    float hr0 = bhh0[j], hz0 = bhh0[32 + j], hn0 = bhh0[64 + j];
    float br1 = bih1[j], bz1 = bih1[32 + j], bn1 = bih1[64 + j];
    float hr1 = bhh1[j], hz1 = bhh1[32 + j], hn1 = bhh1[64 + j];
    __syncthreads();

#pragma unroll 1
    for (int tile = 0; tile < 4; tile++) {
        int node0 = (blockIdx.x * 4 + tile) * 32 + g * 4;
#pragma unroll
        for (int i = 0; i < 4; i++) {
            int node = node0 + i;
            rows[g][i][j] = (node < N) ? gat[(size_t)node * Hd + j] : 0.f;
        }
        __syncthreads();

        float o1v[4];
        {
            float ar[4], az[4], an[4];
#pragma unroll
            for (int i = 0; i < 4; i++) { ar[i] = br0; az[i] = bz0; an[i] = bn0; }
#pragma unroll
            for (int k4 = 0; k4 < 8; k4++) {
                float4 wr = *(const float4*)&W0[(j     ) * WP + k4 * 4];
                float4 wz = *(const float4*)&W0[(32 + j) * WP + k4 * 4];
                float4 wn = *(const float4*)&W0[(64 + j) * WP + k4 * 4];
#pragma unroll
                for (int i = 0; i < 4; i++) {
                    float4 xv = *(const float4*)&rows[g][i][k4 * 4];
                    ar[i] = fmaf(xv.x, wr.x, ar[i]); ar[i] = fmaf(xv.y, wr.y, ar[i]);
                    ar[i] = fmaf(xv.z, wr.z, ar[i]); ar[i] = fmaf(xv.w, wr.w, ar[i]);
                    az[i] = fmaf(xv.x, wz.x, az[i]); az[i] = fmaf(xv.y, wz.y, az[i]);
                    az[i] = fmaf(xv.z, wz.z, az[i]); az[i] = fmaf(xv.w, wz.w, az[i]);
                    an[i] = fmaf(xv.x, wn.x, an[i]); an[i] = fmaf(xv.y, wn.y, an[i]);
                    an[i] = fmaf(xv.z, wn.z, an[i]); an[i] = fmaf(xv.w, wn.w, an[i]);
                }
            }
#pragma unroll
            for (int i = 0; i < 4; i++) {
                float r = fsigm(ar[i] + hr0);
                float z = fsigm(az[i] + hz0);
                float t = ftanh(an[i] + r * hn0);
                o1v[i] = (1.f - z) * t;
            }
        }
        __syncthreads();
#pragma unroll
        for (int i = 0; i < 4; i++) rows[g][i][j] = o1v[i];
        __syncthreads();
        {
            float ar[4], az[4], an[4];
#pragma unroll
            for (int i = 0; i < 4; i++) { ar[i] = br1; az[i] = bz1; an[i] = bn1; }
#pragma unroll
            for (int k4 = 0; k4 < 8; k4++) {
                float4 wr = *(const float4*)&W1[(j     ) * WP + k4 * 4];
                float4 wz = *(const float4*)&W1[(32 + j) * WP + k4 * 4];
                float4 wn = *(const float4*)&W1[(64 + j) * WP + k4 * 4];
#pragma unroll
                for (int i = 0; i < 4; i++) {
                    float4 xv = *(const float4*)&rows[g][i][k4 * 4];
                    ar[i] = fmaf(xv.x, wr.x, ar[i]); ar[i] = fmaf(xv.y, wr.y, ar[i]);
                    ar[i] = fmaf(xv.z, wr.z, ar[i]); ar[i] = fmaf(xv.w, wr.w, ar[i]);
                    az[i] = fmaf(xv.x, wz.x, az[i]); az[i] = fmaf(xv.y, wz.y, az[i]);
                    az[i] = fmaf(xv.z, wz.z, az[i]); az[i] = fmaf(xv.w, wz.w, az[i]);
                    an[i] = fmaf(xv.x, wn.x, an[i]); an[i] = fmaf(xv.y, wn.y, an[i]);
                    an[i] = fmaf(xv.z, wn.z, an[i]); an[i] = fmaf(xv.w, wn.w, an[i]);
                }
            }
#pragma unroll
            for (int i = 0; i < 4; i++) {
                float r = fsigm(ar[i] + hr1);
                float z = fsigm(az[i] + hz1);
                float t = ftanh(an[i] + r * hn1);
                int node = node0 + i;
                if (node < N) out[(size_t)node * Hd + j] = (1.f - z) * t;
            }
        }
        __syncthreads();   // rows reused next tile
    }
}

extern "C" void kernel_launch(void* const* d_in, const int* in_sizes, int n_in,
                              void* d_out, int out_size, void* d_ws, size_t ws_size,
                              hipStream_t stream)
{
    const float* x    = (const float*)d_in[0];
    const int*   ei   = (const int*)d_in[1];
    const float* W    = (const float*)d_in[2];
    const float* atts = (const float*)d_in[3];
    const float* attd = (const float*)d_in[4];
    const float* bias = (const float*)d_in[5];
    const float* Wih0 = (const float*)d_in[6];
    const float* bih0 = (const float*)d_in[8];
    const float* bhh0 = (const float*)d_in[9];
    const float* Wih1 = (const float*)d_in[10];
    const float* bih1 = (const float*)d_in[12];
    const float* bhh1 = (const float*)d_in[13];
    const float* linW = (const float*)d_in[14];
    const float* linb = (const float*)d_in[15];

    int N = in_sizes[0] / Hd;
    int E = in_sizes[1] / 2;
    const int* src = ei;
    const int* dst = ei + E;
    int nbuck = (N + BN - 1) >> BSH;          // 196 for N=100000
    int nchunk = (E + CHUNK - 1) / CHUNK;     // 293 for E=2.4M
    int L = nbuck * nchunk;                   // 57428
    int nbL = (L + 255) / 256;                // 225 (<=512)

    // workspace carve (every slot rewritten before any read, each launch)
    float* h     = (float*)d_ws;                 // [N,32]
    float* gat   = h   + (size_t)N * Hd;         // [N,32]  (tmp aliases this)
    float* h2    = gat + (size_t)N * Hd;         // [N,32]
    float* as_   = h2  + (size_t)N * Hd;         // [N]
    float* ad_   = as_ + N;                      // [N]
    int*   cnt   = (int*)(ad_ + N);              // [N]
    int*   off   = cnt + N;                      // [N]
    int*   counts= off + N;                      // [L]
    int*   cstart= counts + L;                   // [L]
    int*   bsum  = cstart + L;                   // [512]
    int*   csr   = bsum + 512;                   // [E]
    unsigned* tmp = (unsigned*)gat;              // [E] aliases gat (disjoint lifetime)

    dim3 blk(256);
    dim3 g_node8((N + 7) / 8);
    dim3 g_nf((N * Hd + 255) / 256);
    dim3 g_gru((N + 127) / 128);

    // ---- CSR build (once; shared by both GAT passes) ----
    hipLaunchKernelGGL(k_histb, dim3(nchunk), blk, 0, stream, dst, counts, E, nchunk, nbuck);
    hipLaunchKernelGGL(k_scan1, dim3(nbL), blk, 0, stream, counts, bsum, L);
    hipLaunchKernelGGL(k_scan2, dim3(1), dim3(512), 0, stream, bsum, nbL);
    hipLaunchKernelGGL(k_scan3, dim3(nbL), blk, 0, stream, counts, bsum, cstart, L);
    hipLaunchKernelGGL(k_scatterb, dim3(nchunk), blk, 0, stream, src, dst, cstart, tmp, E, nchunk, nbuck);
    hipLaunchKernelGGL(k_place2, dim3(nbuck), blk, 0, stream, tmp, cstart, csr, off, cnt, N, E, nchunk, nbuck);

    // ---- GAT pass 1 (input = relu(x)) + GRU0 + GRU1 ----
    hipLaunchKernelGGL((k_node_proj<true>), g_node8, blk, 0, stream, x, W, atts, attd, h, as_, ad_, N);
    hipLaunchKernelGGL((k_gather<0>), g_nf, blk, 0, stream, h, as_, ad_, cnt, off, csr, bias, linW, linb, gat, N);
    hipLaunchKernelGGL(k_finish_gru, g_gru, blk, 0, stream, gat,
                       Wih0, bih0, bhh0, Wih1, bih1, bhh1, h2, N);

    // ---- GAT pass 2 (input = h2) + fused linear ----
    hipLaunchKernelGGL((k_node_proj<false>), g_node8, blk, 0, stream, h2, W, atts, attd, h, as_, ad_, N);
    hipLaunchKernelGGL((k_gather<1>), g_nf, blk, 0, stream, h, as_, ad_, cnt, off, csr, bias, linW, linb, (float*)d_out, N);
}